// Round 1
// baseline (877.963 us; speedup 1.0000x reference)
//
#include <hip/hip_runtime.h>
#include <math.h>

#define CC 64
#define CQv 8
#define CRv 4
#define BB 4
#define RR 224
#define TT 224
#define NN (RR*TT)   // 50176

// ---------------- K1: q,k,v 1x1 convs ----------------
// grid: BB*RR blocks, 256 threads (t = threadIdx.x < 224 active)
// qB[b][r][t][8], kB[b][r][t][8], vB[b][r][t][64]
__global__ __launch_bounds__(256) void k_qkv(
    const float* __restrict__ x,
    const float* __restrict__ Wq, const float* __restrict__ bq,
    const float* __restrict__ Wk, const float* __restrict__ bk,
    const float* __restrict__ Wv, const float* __restrict__ bv,
    float* __restrict__ qB, float* __restrict__ kB, float* __restrict__ vB)
{
    int blk = blockIdx.x;
    int b = blk / RR, r = blk - b*RR;
    int t = threadIdx.x;
    if (t >= TT) return;
    const float* xp = x + (size_t)b*CC*NN + (size_t)r*TT + t;
    float xr[CC];
#pragma unroll
    for (int c = 0; c < CC; ++c) xr[c] = xp[(size_t)c*NN];

    float* qp = qB + ((size_t)blk*TT + t)*CQv;
    float* kp = kB + ((size_t)blk*TT + t)*CQv;
    float* vp = vB + ((size_t)blk*TT + t)*CC;

#pragma unroll
    for (int o = 0; o < CQv; ++o) {
        float aq = bq[o], ak = bk[o];
#pragma unroll
        for (int c = 0; c < CC; ++c) {
            aq += Wq[o*CC + c] * xr[c];
            ak += Wk[o*CC + c] * xr[c];
        }
        qp[o] = aq; kp[o] = ak;
    }
#pragma unroll 4
    for (int o = 0; o < CC; ++o) {
        float av = bv[o];
#pragma unroll
        for (int c = 0; c < CC; ++c) av += Wv[o*CC + c] * xr[c];
        vp[o] = av;
    }
}

// ---------------- transpose [b][r][t][CB] -> [b][t][r][CB] ----------------
template<int CB, int TILE, int PAD>
__global__ __launch_bounds__(256) void k_permRT(const float* __restrict__ src,
                                                float* __restrict__ dst)
{
    constexpr int ROWLEN = TILE*CB;
    __shared__ float tile[TILE*(ROWLEN+PAD)];
    int b  = blockIdx.z;
    int t0 = blockIdx.x*TILE, r0 = blockIdx.y*TILE;
    const size_t plane = (size_t)RR*TT*CB;
    const float* sp = src + (size_t)b*plane;
    float*       dp = dst + (size_t)b*plane;
    for (int idx = threadIdx.x; idx < TILE*ROWLEN; idx += 256) {
        int lr = idx / ROWLEN, rem = idx - lr*ROWLEN;
        tile[lr*(ROWLEN+PAD) + rem] = sp[(size_t)(r0+lr)*(TT*CB) + (size_t)t0*CB + rem];
    }
    __syncthreads();
    for (int idx = threadIdx.x; idx < TILE*ROWLEN; idx += 256) {
        int lt = idx / ROWLEN, rem = idx - lt*ROWLEN;
        int lr = rem / CB, c = rem - lr*CB;
        dp[(size_t)(t0+lt)*(RR*CB) + (size_t)r0*CB + rem] = tile[lr*(ROWLEN+PAD) + lt*CB + c];
    }
}

// ---------------- scores: per-(b,slice) row stats ----------------
// HM: slabs [b][t][r][8] from qA/kA, stats at [b][r][t] (stride TT)
// !HM: slabs [b][r][t][8] from qB/kB, stats at [b][r][t] (stride 1)
template<bool HM>
__global__ __launch_bounds__(256) void k_scores(const float* __restrict__ Qsrc,
                                                const float* __restrict__ Ksrc,
                                                float* __restrict__ M, float* __restrict__ Z)
{
    __shared__ float Qs[RR*CQv], Ks[RR*CQv];
    int blk = blockIdx.x;
    int b = blk / 224, o = blk - b*224;
    const float4* qp = (const float4*)(Qsrc + (size_t)blk*(224*CQv));
    const float4* kp = (const float4*)(Ksrc + (size_t)blk*(224*CQv));
    for (int i = threadIdx.x; i < 448; i += 256) {
        ((float4*)Qs)[i] = qp[i];
        ((float4*)Ks)[i] = kp[i];
    }
    __syncthreads();
    int r = threadIdx.x;
    if (r >= 224) return;
    float4 qa = *(float4*)&Qs[r*8], qb = *(float4*)&Qs[r*8+4];
    float m = -1e30f;
    for (int u = 0; u < 224; ++u) {
        float4 ka = *(float4*)&Ks[u*8], kb = *(float4*)&Ks[u*8+4];
        float e = qa.x*ka.x + qa.y*ka.y + qa.z*ka.z + qa.w*ka.w
                + qb.x*kb.x + qb.y*kb.y + qb.z*kb.z + qb.w*kb.w;
        if (!(HM && u == r)) m = fmaxf(m, e);
    }
    float z = 0.f;
    for (int u = 0; u < 224; ++u) {
        float4 ka = *(float4*)&Ks[u*8], kb = *(float4*)&Ks[u*8+4];
        float e = qa.x*ka.x + qa.y*ka.y + qa.z*ka.z + qa.w*ka.w
                + qb.x*kb.x + qb.y*kb.y + qb.z*kb.z + qb.w*kb.w;
        if (!(HM && u == r)) z += __expf(e - m);
    }
    size_t sidx = HM ? ((size_t)b*NN + (size_t)r*TT + o)
                     : ((size_t)b*NN + (size_t)o*TT + r);
    M[sidx] = m; Z[sidx] = z;
}

// ---------------- combine H/W stats ----------------
__global__ __launch_bounds__(256) void k_combine(const float* __restrict__ MH, const float* __restrict__ ZH,
                                                 const float* __restrict__ MW, const float* __restrict__ ZW,
                                                 float* __restrict__ Mf, float* __restrict__ Zi)
{
    int i = blockIdx.x*256 + threadIdx.x;
    if (i >= BB*NN) return;
    float mh = MH[i], mw = MW[i];
    float m = fmaxf(mh, mw);
    float z = ZH[i]*__expf(mh - m) + ZW[i]*__expf(mw - m);
    Mf[i] = m; Zi[i] = 1.f/z;
}

// ---------------- PV: recompute logits, exp, contract with V ----------------
// HM: writes outA slab [b][t][c][r] (full store, gamma applied)
// !HM: RMW-accumulates gamma*outW into d_out at [b][c][r=o][t]
template<bool HM>
__global__ __launch_bounds__(256) void k_pv(const float* __restrict__ Qsrc,
                                            const float* __restrict__ Ksrc,
                                            const float* __restrict__ Vsrc,
                                            const float* __restrict__ Mf, const float* __restrict__ Zi,
                                            const float* __restrict__ gammap,
                                            float* __restrict__ outp)
{
    __shared__ float Qs[224*8];
    __shared__ float Ks[224*8];
    __shared__ float Vs[224*64];     // [u][c]
    __shared__ float As[32*228];     // [rl][u], padded
    __shared__ float Ml[224], Zl[224];
    int blk = blockIdx.x;
    int b = blk / 224, o = blk - b*224;
    float g = gammap[0];
    const float4* qp = (const float4*)(Qsrc + (size_t)blk*1792);
    const float4* kp = (const float4*)(Ksrc + (size_t)blk*1792);
    const float4* vp = (const float4*)(Vsrc + (size_t)blk*14336);
    for (int i = threadIdx.x; i < 448; i += 256) {
        ((float4*)Qs)[i] = qp[i];
        ((float4*)Ks)[i] = kp[i];
    }
    for (int i = threadIdx.x; i < 3584; i += 256) ((float4*)Vs)[i] = vp[i];
    if (threadIdx.x < 224) {
        size_t sidx = HM ? ((size_t)b*NN + (size_t)threadIdx.x*TT + o)
                         : ((size_t)b*NN + (size_t)o*TT + threadIdx.x);
        Ml[threadIdx.x] = Mf[sidx];
        Zl[threadIdx.x] = Zi[sidx];
    }
    __syncthreads();

    const int rl   = threadIdx.x >> 3;        // 0..31 (score phase row)
    const int usub = threadIdx.x & 7;         // 0..7
    const int c0   = (threadIdx.x & 15) * 4;  // PV: 4 channels
    const int rg   = threadIdx.x >> 4;        // PV: 2 rows (rg*2, rg*2+1)

    float* op;
    if (HM) op = outp + (size_t)blk*14336;                       // [c][r] slab
    else    op = outp + (size_t)b*CC*NN + (size_t)o*TT;          // + c*NN + t

    for (int chunk = 0; chunk < 7; ++chunk) {
        const int r0 = chunk*32;
        {   // score phase
            int r = r0 + rl;
            float4 qa = *(float4*)&Qs[r*8], qb = *(float4*)&Qs[r*8+4];
            float m = Ml[r], zi = Zl[r];
            for (int k2 = 0; k2 < 28; ++k2) {
                int u = usub*28 + k2;
                float4 ka = *(float4*)&Ks[u*8], kb = *(float4*)&Ks[u*8+4];
                float e = qa.x*ka.x + qa.y*ka.y + qa.z*ka.z + qa.w*ka.w
                        + qb.x*kb.x + qb.y*kb.y + qb.z*kb.z + qb.w*kb.w;
                float att = __expf(e - m) * zi;
                if (HM && u == r) att = 0.f;
                As[rl*228 + u] = att;
            }
        }
        __syncthreads();
        {   // PV phase
            float acc[4][2];
#pragma unroll
            for (int ci = 0; ci < 4; ++ci) { acc[ci][0] = 0.f; acc[ci][1] = 0.f; }
            const int ra = (rg*2)*228, rb = (rg*2+1)*228;
#pragma unroll 2
            for (int u = 0; u < 224; u += 4) {
                float4 a0 = *(float4*)&As[ra + u];
                float4 a1 = *(float4*)&As[rb + u];
                float4 v0 = *(float4*)&Vs[(u+0)*64 + c0];
                float4 v1 = *(float4*)&Vs[(u+1)*64 + c0];
                float4 v2 = *(float4*)&Vs[(u+2)*64 + c0];
                float4 v3 = *(float4*)&Vs[(u+3)*64 + c0];
                acc[0][0] += v0.x*a0.x + v1.x*a0.y + v2.x*a0.z + v3.x*a0.w;
                acc[1][0] += v0.y*a0.x + v1.y*a0.y + v2.y*a0.z + v3.y*a0.w;
                acc[2][0] += v0.z*a0.x + v1.z*a0.y + v2.z*a0.z + v3.z*a0.w;
                acc[3][0] += v0.w*a0.x + v1.w*a0.y + v2.w*a0.z + v3.w*a0.w;
                acc[0][1] += v0.x*a1.x + v1.x*a1.y + v2.x*a1.z + v3.x*a1.w;
                acc[1][1] += v0.y*a1.x + v1.y*a1.y + v2.y*a1.z + v3.y*a1.w;
                acc[2][1] += v0.z*a1.x + v1.z*a1.y + v2.z*a1.z + v3.z*a1.w;
                acc[3][1] += v0.w*a1.x + v1.w*a1.y + v2.w*a1.z + v3.w*a1.w;
            }
            if (HM) {
#pragma unroll
                for (int ci = 0; ci < 4; ++ci)
#pragma unroll
                    for (int rj = 0; rj < 2; ++rj)
                        op[(size_t)(c0+ci)*224 + (r0 + rg*2 + rj)] = g*acc[ci][rj];
            } else {
#pragma unroll
                for (int ci = 0; ci < 4; ++ci)
#pragma unroll
                    for (int rj = 0; rj < 2; ++rj) {
                        size_t a = (size_t)(c0+ci)*NN + (size_t)(r0 + rg*2 + rj);
                        op[a] += g*acc[ci][rj];
                    }
            }
        }
        __syncthreads();
    }
}

// ---------------- SE branch ----------------
__global__ __launch_bounds__(256) void k_mean(const float* __restrict__ x, float* __restrict__ yMean)
{
    int bc = blockIdx.x;
    const float* xp = x + (size_t)bc*NN;
    float s = 0.f;
    for (int i = threadIdx.x; i < NN; i += 256) s += xp[i];
#pragma unroll
    for (int off = 32; off > 0; off >>= 1) s += __shfl_down(s, off);
    __shared__ float red[4];
    if ((threadIdx.x & 63) == 0) red[threadIdx.x >> 6] = s;
    __syncthreads();
    if (threadIdx.x == 0) yMean[bc] = (red[0]+red[1]+red[2]+red[3]) * (1.0f/NN);
}

__global__ __launch_bounds__(256) void k_se2(const float* __restrict__ yMean,
                                             const float* __restrict__ W1,
                                             const float* __restrict__ W2,
                                             float* __restrict__ y2)
{
    int tid = threadIdx.x;
    int b = tid >> 6, c = tid & 63;
    float h[CRv];
#pragma unroll
    for (int j = 0; j < CRv; ++j) {
        float s = 0.f;
#pragma unroll
        for (int cc = 0; cc < CC; ++cc) s += W1[j*CC + cc] * yMean[b*CC + cc];
        h[j] = fmaxf(s, 0.f);
    }
    float s2 = 0.f;
#pragma unroll
    for (int j = 0; j < CRv; ++j) s2 += W2[c*CRv + j] * h[j];
    y2[tid] = 1.f/(1.f + __expf(-s2));
}

// ---------------- final: out = x*(1+y2) + outA^T ----------------
__global__ __launch_bounds__(256) void k_final(const float* __restrict__ x,
                                               const float* __restrict__ outA,
                                               const float* __restrict__ y2,
                                               float* __restrict__ out)
{
    __shared__ float tile[32][33];
    int bc = blockIdx.z;
    int b = bc >> 6, c = bc & 63;
    int t0 = blockIdx.x*32, r0 = blockIdx.y*32;
    int tx = threadIdx.x & 31, ty = threadIdx.x >> 5;
    float scale = 1.f + y2[bc];
#pragma unroll
    for (int j = 0; j < 4; ++j) {
        int tl = ty + 8*j;
        tile[tl][tx] = outA[((size_t)(b*224 + t0 + tl)*64 + c)*224 + r0 + tx];
    }
    __syncthreads();
#pragma unroll
    for (int j = 0; j < 4; ++j) {
        int rl = ty + 8*j;
        size_t idx = ((size_t)bc*224 + (r0 + rl))*224 + t0 + tx;
        out[idx] = x[idx]*scale + tile[tx][rl];
    }
}

// ---------------- launcher ----------------
extern "C" void kernel_launch(void* const* d_in, const int* in_sizes, int n_in,
                              void* d_out, int out_size, void* d_ws, size_t ws_size,
                              hipStream_t stream)
{
    const float* x  = (const float*)d_in[0];
    const float* Wq = (const float*)d_in[1];
    const float* bq = (const float*)d_in[2];
    const float* Wk = (const float*)d_in[3];
    const float* bk = (const float*)d_in[4];
    const float* Wv = (const float*)d_in[5];
    const float* bv = (const float*)d_in[6];
    const float* gm = (const float*)d_in[7];
    const float* W1 = (const float*)d_in[8];
    const float* W2 = (const float*)d_in[9];
    float* out = (float*)d_out;
    float* ws  = (float*)d_ws;

    constexpr size_t QSZ = (size_t)BB*RR*TT*CQv;   // 1,605,632
    constexpr size_t VSZ = (size_t)BB*RR*TT*CC;    // 12,845,056
    constexpr size_t SSZ = (size_t)BB*RR*TT;       // 200,704

    float* qB = ws;
    float* kB = qB + QSZ;
    float* vB = kB + QSZ;
    float* qA = vB + VSZ;
    float* kA = qA + QSZ;
    float* vA = kA + QSZ;
    float* MH = vA + VSZ;
    float* ZH = MH + SSZ;
    float* MW = ZH + SSZ;
    float* ZW = MW + SSZ;
    float* Mf = ZW + SSZ;
    float* Zi = Mf + SSZ;
    float* outA  = Zi + SSZ;
    float* yMean = outA + VSZ;
    float* y2    = yMean + 256;
    (void)ws_size; (void)in_sizes; (void)n_in; (void)out_size;

    k_qkv<<<BB*RR, 256, 0, stream>>>(x, Wq, bq, Wk, bk, Wv, bv, qB, kB, vB);
    k_permRT<8,32,8><<<dim3(7,7,BB), 256, 0, stream>>>(qB, qA);
    k_permRT<8,32,8><<<dim3(7,7,BB), 256, 0, stream>>>(kB, kA);
    k_permRT<64,16,0><<<dim3(14,14,BB), 256, 0, stream>>>(vB, vA);

    k_scores<true ><<<BB*224, 256, 0, stream>>>(qA, kA, MH, ZH);
    k_scores<false><<<BB*224, 256, 0, stream>>>(qB, kB, MW, ZW);
    k_combine<<<(BB*NN + 255)/256, 256, 0, stream>>>(MH, ZH, MW, ZW, Mf, Zi);

    k_pv<true><<<BB*224, 256, 0, stream>>>(qA, kA, vA, Mf, Zi, gm, outA);

    k_mean<<<BB*CC, 256, 0, stream>>>(x, yMean);
    k_se2<<<1, 256, 0, stream>>>(yMean, W1, W2, y2);
    k_final<<<dim3(7,7,BB*CC), 256, 0, stream>>>(x, outA, y2, out);

    k_pv<false><<<BB*224, 256, 0, stream>>>(qB, kB, vB, Mf, Zi, gm, out);
}

// Round 2
// 489.351 us; speedup vs baseline: 1.7941x; 1.7941x over previous
//
#include <hip/hip_runtime.h>
#include <math.h>

#define CC 64
#define CQv 8
#define CRv 4
#define BB 4
#define RR 224
#define TT 224
#define NN (RR*TT)   // 50176

typedef __attribute__((ext_vector_type(8))) short short8;
typedef __attribute__((ext_vector_type(4))) float f32x4;

__device__ __forceinline__ f32x4 mfma_bf16(short8 a, short8 b, f32x4 c){
    return __builtin_amdgcn_mfma_f32_16x16x32_bf16(a, b, c, 0, 0, 0);
}

__device__ __forceinline__ ushort f2bf(float f){
    union { float f; unsigned u; } v; v.f = f;
    unsigned r = v.u + 0x7fffu + ((v.u >> 16) & 1u);
    return (ushort)(r >> 16);
}

// ---------------- K1: q,k,v 1x1 convs ----------------
__global__ __launch_bounds__(256) void k_qkv(
    const float* __restrict__ x,
    const float* __restrict__ Wq, const float* __restrict__ bq,
    const float* __restrict__ Wk, const float* __restrict__ bk,
    const float* __restrict__ Wv, const float* __restrict__ bv,
    float* __restrict__ qB, float* __restrict__ kB, float* __restrict__ vB)
{
    int blk = blockIdx.x;
    int b = blk / RR, r = blk - b*RR;
    int t = threadIdx.x;
    if (t >= TT) return;
    const float* xp = x + (size_t)b*CC*NN + (size_t)r*TT + t;
    float xr[CC];
#pragma unroll
    for (int c = 0; c < CC; ++c) xr[c] = xp[(size_t)c*NN];

    float* qp = qB + ((size_t)blk*TT + t)*CQv;
    float* kp = kB + ((size_t)blk*TT + t)*CQv;
    float* vp = vB + ((size_t)blk*TT + t)*CC;

#pragma unroll
    for (int o = 0; o < CQv; ++o) {
        float aq = bq[o], ak = bk[o];
#pragma unroll
        for (int c = 0; c < CC; ++c) {
            aq += Wq[o*CC + c] * xr[c];
            ak += Wk[o*CC + c] * xr[c];
        }
        qp[o] = aq; kp[o] = ak;
    }
#pragma unroll 4
    for (int o = 0; o < CC; ++o) {
        float av = bv[o];
#pragma unroll
        for (int c = 0; c < CC; ++c) av += Wv[o*CC + c] * xr[c];
        vp[o] = av;
    }
}

// ---------------- transpose [b][r][t][CB] -> [b][t][r][CB] ----------------
template<int CB, int TILE, int PAD>
__global__ __launch_bounds__(256) void k_permRT(const float* __restrict__ src,
                                                float* __restrict__ dst)
{
    constexpr int ROWLEN = TILE*CB;
    __shared__ float tile[TILE*(ROWLEN+PAD)];
    int b  = blockIdx.z;
    int t0 = blockIdx.x*TILE, r0 = blockIdx.y*TILE;
    const size_t plane = (size_t)RR*TT*CB;
    const float* sp = src + (size_t)b*plane;
    float*       dp = dst + (size_t)b*plane;
    for (int idx = threadIdx.x; idx < TILE*ROWLEN; idx += 256) {
        int lr = idx / ROWLEN, rem = idx - lr*ROWLEN;
        tile[lr*(ROWLEN+PAD) + rem] = sp[(size_t)(r0+lr)*(TT*CB) + (size_t)t0*CB + rem];
    }
    __syncthreads();
    for (int idx = threadIdx.x; idx < TILE*ROWLEN; idx += 256) {
        int lt = idx / ROWLEN, rem = idx - lt*ROWLEN;
        int lr = rem / CB, c = rem - lr*CB;
        dp[(size_t)(t0+lt)*(RR*CB) + (size_t)r0*CB + rem] = tile[lr*(ROWLEN+PAD) + lt*CB + c];
    }
}

// ---------------- scores: per-(b,slice) row stats ----------------
template<bool HM>
__global__ __launch_bounds__(256) void k_scores(const float* __restrict__ Qsrc,
                                                const float* __restrict__ Ksrc,
                                                float* __restrict__ M, float* __restrict__ Z)
{
    __shared__ float Qs[RR*CQv], Ks[RR*CQv];
    int blk = blockIdx.x;
    int b = blk / 224, o = blk - b*224;
    const float4* qp = (const float4*)(Qsrc + (size_t)blk*(224*CQv));
    const float4* kp = (const float4*)(Ksrc + (size_t)blk*(224*CQv));
    for (int i = threadIdx.x; i < 448; i += 256) {
        ((float4*)Qs)[i] = qp[i];
        ((float4*)Ks)[i] = kp[i];
    }
    __syncthreads();
    int r = threadIdx.x;
    if (r >= 224) return;
    float4 qa = *(float4*)&Qs[r*8], qb = *(float4*)&Qs[r*8+4];
    float m = -1e30f;
    for (int u = 0; u < 224; ++u) {
        float4 ka = *(float4*)&Ks[u*8], kb = *(float4*)&Ks[u*8+4];
        float e = qa.x*ka.x + qa.y*ka.y + qa.z*ka.z + qa.w*ka.w
                + qb.x*kb.x + qb.y*kb.y + qb.z*kb.z + qb.w*kb.w;
        if (!(HM && u == r)) m = fmaxf(m, e);
    }
    float z = 0.f;
    for (int u = 0; u < 224; ++u) {
        float4 ka = *(float4*)&Ks[u*8], kb = *(float4*)&Ks[u*8+4];
        float e = qa.x*ka.x + qa.y*ka.y + qa.z*ka.z + qa.w*ka.w
                + qb.x*kb.x + qb.y*kb.y + qb.z*kb.z + qb.w*kb.w;
        if (!(HM && u == r)) z += __expf(e - m);
    }
    size_t sidx = HM ? ((size_t)b*NN + (size_t)r*TT + o)
                     : ((size_t)b*NN + (size_t)o*TT + r);
    M[sidx] = m; Z[sidx] = z;
}

// ---------------- combine H/W stats ----------------
__global__ __launch_bounds__(256) void k_combine(const float* __restrict__ MH, const float* __restrict__ ZH,
                                                 const float* __restrict__ MW, const float* __restrict__ ZW,
                                                 float* __restrict__ Mf, float* __restrict__ Zi)
{
    int i = blockIdx.x*256 + threadIdx.x;
    if (i >= BB*NN) return;
    float mh = MH[i], mw = MW[i];
    float m = fmaxf(mh, mw);
    float z = ZH[i]*__expf(mh - m) + ZW[i]*__expf(mw - m);
    Mf[i] = m; Zi[i] = 1.f/z;
}

// ---------------- PV via MFMA: logits (K=8 padded to 32) + PV contraction ----------------
// HM: writes outA slab [b][t][c][r]; !HM: RMW gamma*outW into d_out at [b][c][o][t]
template<bool HM>
__global__ __launch_bounds__(256, 3) void k_pv(const float* __restrict__ Qsrc,
                                               const float* __restrict__ Ksrc,
                                               const float* __restrict__ Vsrc,
                                               const float* __restrict__ Mf, const float* __restrict__ Zi,
                                               const float* __restrict__ gammap,
                                               float* __restrict__ outp)
{
    __shared__ __align__(16) ushort Qh[224*8];   // bf16 rows of 16B
    __shared__ __align__(16) ushort Kh[224*8];
    __shared__ __align__(16) ushort Vt[64*224];  // bf16 [c][u], slot-swizzled
    __shared__ __align__(16) ushort Ah[32*224];  // bf16 [rl][u], slot-swizzled
    __shared__ float Ml[224], Zl[224];

    const int tid = threadIdx.x;
    const int blk = blockIdx.x;
    const int b = blk / 224, o = blk - b*224;
    const float g = gammap[0];

    // ---- stage Q,K as bf16
    {
        const float4* qp = (const float4*)(Qsrc + (size_t)blk*1792);
        const float4* kp = (const float4*)(Ksrc + (size_t)blk*1792);
        for (int i = tid; i < 448; i += 256) {
            float4 qv = qp[i]; float4 kv = kp[i];
            ushort4 qh, kh;
            qh.x = f2bf(qv.x); qh.y = f2bf(qv.y); qh.z = f2bf(qv.z); qh.w = f2bf(qv.w);
            kh.x = f2bf(kv.x); kh.y = f2bf(kv.y); kh.z = f2bf(kv.z); kh.w = f2bf(kv.w);
            ((ushort4*)Qh)[i] = qh;
            ((ushort4*)Kh)[i] = kh;
        }
    }
    // ---- stage V transposed bf16, swizzled: byte = c*448 + slot*16 + (u&7)*2,
    //      slot = ((u>>3) + (c&7)) mod 28   (bijective per row, spreads banks)
    {
        const float4* vp = (const float4*)(Vsrc + (size_t)blk*14336);
        char* vb = (char*)Vt;
        for (int i = tid; i < 3584; i += 256) {
            float4 vv = vp[i];
            int u = i >> 4, c0 = (i & 15)*4;
            float vals[4] = {vv.x, vv.y, vv.z, vv.w};
#pragma unroll
            for (int j = 0; j < 4; ++j) {
                int c = c0 + j;
                int slot = (u >> 3) + (c & 7); slot -= (slot >= 28) ? 28 : 0;
                *(ushort*)(vb + c*448 + slot*16 + (u & 7)*2) = f2bf(vals[j]);
            }
        }
    }
    if (tid < 224) {
        size_t sidx = HM ? ((size_t)b*NN + (size_t)tid*TT + o)
                         : ((size_t)b*NN + (size_t)o*TT + tid);
        Ml[tid] = Mf[sidx];
        Zl[tid] = Zi[sidx];
    }
    __syncthreads();

    const int w = tid >> 6, l = tid & 63;
    const int l15 = l & 15, lg = l >> 4;

    // hoisted Vt fragments (A-operand rows = channels c0..c0+15 of this wave)
    short8 vfr[7];
    {
        const char* vb = (const char*)Vt;
        int c = w*16 + l15;
#pragma unroll
        for (int ks = 0; ks < 7; ++ks) {
            int u = ks*32 + lg*8;
            int slot = (u >> 3) + (c & 7); slot -= (slot >= 28) ? 28 : 0;
            vfr[ks] = *(const short8*)(vb + c*448 + slot*16);
        }
    }

    float* op;
    if (HM) op = outp + (size_t)blk*14336;                   // [c][r] slab
    else    op = outp + (size_t)b*CC*NN + (size_t)o*TT;      // + c*NN + t

    const short8 zfr = {0,0,0,0,0,0,0,0};
    const f32x4 zacc = {0.f,0.f,0.f,0.f};

    for (int ch = 0; ch < 7; ++ch) {
        const int r0 = ch*32;
        // ---- score phase: e[u,r] = K·Q^T via MFMA (8 real K-comps, rest zero)
        {
            short8 qf[2];
            float mreg[2], zreg[2];
#pragma unroll
            for (int rt = 0; rt < 2; ++rt) {
                int r = r0 + rt*16 + l15;
                qf[rt] = zfr;
                if (lg == 0) qf[rt] = *(const short8*)(Qh + r*8);
                mreg[rt] = Ml[r]; zreg[rt] = Zl[r];
            }
#pragma unroll
            for (int j = 0; j < 4; ++j) {
                int ut = w + 4*j;
                if (ut < 14) {
                    short8 kf = zfr;
                    if (lg == 0) kf = *(const short8*)(Kh + (ut*16 + l15)*8);
#pragma unroll
                    for (int rt = 0; rt < 2; ++rt) {
                        f32x4 e = mfma_bf16(kf, qf[rt], zacc);
                        int ubase = ut*16 + lg*4;
                        int r = r0 + rt*16 + l15;
                        float att0 = __expf(e[0]-mreg[rt])*zreg[rt];
                        float att1 = __expf(e[1]-mreg[rt])*zreg[rt];
                        float att2 = __expf(e[2]-mreg[rt])*zreg[rt];
                        float att3 = __expf(e[3]-mreg[rt])*zreg[rt];
                        if (HM) {
                            if (ubase+0 == r) att0 = 0.f;
                            if (ubase+1 == r) att1 = 0.f;
                            if (ubase+2 == r) att2 = 0.f;
                            if (ubase+3 == r) att3 = 0.f;
                        }
                        unsigned lo = (unsigned)f2bf(att0) | ((unsigned)f2bf(att1) << 16);
                        unsigned hi = (unsigned)f2bf(att2) | ((unsigned)f2bf(att3) << 16);
                        int rl = rt*16 + l15;
                        int slot = (ubase >> 3) + (rl & 7); slot -= (slot >= 28) ? 28 : 0;
                        uint2 pk; pk.x = lo; pk.y = hi;
                        *(uint2*)((char*)Ah + rl*448 + slot*16 + (ubase & 7)*2) = pk;
                    }
                }
            }
        }
        __syncthreads();
        // ---- PV phase: D[c,r] = Vt · A^T
        {
            const char* ab = (const char*)Ah;
#pragma unroll
            for (int rt = 0; rt < 2; ++rt) {
                f32x4 acc = zacc;
                int rl = rt*16 + l15;
#pragma unroll
                for (int ks = 0; ks < 7; ++ks) {
                    int u = ks*32 + lg*8;
                    int slot = (u >> 3) + (rl & 7); slot -= (slot >= 28) ? 28 : 0;
                    short8 af = *(const short8*)(ab + rl*448 + slot*16);
                    acc = mfma_bf16(vfr[ks], af, acc);
                }
                int c0 = w*16 + lg*4;
                int r = r0 + rt*16 + l15;
                if (HM) {
#pragma unroll
                    for (int reg = 0; reg < 4; ++reg)
                        op[(size_t)(c0+reg)*224 + r] = g*acc[reg];
                } else {
#pragma unroll
                    for (int reg = 0; reg < 4; ++reg) {
                        size_t a = (size_t)(c0+reg)*NN + r;
                        op[a] += g*acc[reg];
                    }
                }
            }
        }
        __syncthreads();
    }
}

// ---------------- SE branch ----------------
__global__ __launch_bounds__(256) void k_mean(const float* __restrict__ x, float* __restrict__ yMean)
{
    int bc = blockIdx.x;
    const float* xp = x + (size_t)bc*NN;
    float s = 0.f;
    for (int i = threadIdx.x; i < NN; i += 256) s += xp[i];
#pragma unroll
    for (int off = 32; off > 0; off >>= 1) s += __shfl_down(s, off);
    __shared__ float red[4];
    if ((threadIdx.x & 63) == 0) red[threadIdx.x >> 6] = s;
    __syncthreads();
    if (threadIdx.x == 0) yMean[bc] = (red[0]+red[1]+red[2]+red[3]) * (1.0f/NN);
}

__global__ __launch_bounds__(256) void k_se2(const float* __restrict__ yMean,
                                             const float* __restrict__ W1,
                                             const float* __restrict__ W2,
                                             float* __restrict__ y2)
{
    int tid = threadIdx.x;
    int b = tid >> 6, c = tid & 63;
    float h[CRv];
#pragma unroll
    for (int j = 0; j < CRv; ++j) {
        float s = 0.f;
#pragma unroll
        for (int cc = 0; cc < CC; ++cc) s += W1[j*CC + cc] * yMean[b*CC + cc];
        h[j] = fmaxf(s, 0.f);
    }
    float s2 = 0.f;
#pragma unroll
    for (int j = 0; j < CRv; ++j) s2 += W2[c*CRv + j] * h[j];
    y2[tid] = 1.f/(1.f + __expf(-s2));
}

// ---------------- final: out = x*(1+y2) + outA^T ----------------
__global__ __launch_bounds__(256) void k_final(const float* __restrict__ x,
                                               const float* __restrict__ outA,
                                               const float* __restrict__ y2,
                                               float* __restrict__ out)
{
    __shared__ float tile[32][33];
    int bc = blockIdx.z;
    int b = bc >> 6, c = bc & 63;
    int t0 = blockIdx.x*32, r0 = blockIdx.y*32;
    int tx = threadIdx.x & 31, ty = threadIdx.x >> 5;
    float scale = 1.f + y2[bc];
#pragma unroll
    for (int j = 0; j < 4; ++j) {
        int tl = ty + 8*j;
        tile[tl][tx] = outA[((size_t)(b*224 + t0 + tl)*64 + c)*224 + r0 + tx];
    }
    __syncthreads();
#pragma unroll
    for (int j = 0; j < 4; ++j) {
        int rl = ty + 8*j;
        size_t idx = ((size_t)bc*224 + (r0 + rl))*224 + t0 + tx;
        out[idx] = x[idx]*scale + tile[tx][rl];
    }
}

// ---------------- launcher ----------------
extern "C" void kernel_launch(void* const* d_in, const int* in_sizes, int n_in,
                              void* d_out, int out_size, void* d_ws, size_t ws_size,
                              hipStream_t stream)
{
    const float* x  = (const float*)d_in[0];
    const float* Wq = (const float*)d_in[1];
    const float* bq = (const float*)d_in[2];
    const float* Wk = (const float*)d_in[3];
    const float* bk = (const float*)d_in[4];
    const float* Wv = (const float*)d_in[5];
    const float* bv = (const float*)d_in[6];
    const float* gm = (const float*)d_in[7];
    const float* W1 = (const float*)d_in[8];
    const float* W2 = (const float*)d_in[9];
    float* out = (float*)d_out;
    float* ws  = (float*)d_ws;

    constexpr size_t QSZ = (size_t)BB*RR*TT*CQv;   // 1,605,632
    constexpr size_t VSZ = (size_t)BB*RR*TT*CC;    // 12,845,056
    constexpr size_t SSZ = (size_t)BB*RR*TT;       // 200,704

    float* qB = ws;
    float* kB = qB + QSZ;
    float* vB = kB + QSZ;
    float* qA = vB + VSZ;
    float* kA = qA + QSZ;
    float* vA = kA + QSZ;
    float* MH = vA + VSZ;
    float* ZH = MH + SSZ;
    float* MW = ZH + SSZ;
    float* ZW = MW + SSZ;
    float* Mf = ZW + SSZ;
    float* Zi = Mf + SSZ;
    float* outA  = Zi + SSZ;
    float* yMean = outA + VSZ;
    float* y2    = yMean + 256;
    (void)ws_size; (void)in_sizes; (void)n_in; (void)out_size;

    k_qkv<<<BB*RR, 256, 0, stream>>>(x, Wq, bq, Wk, bk, Wv, bv, qB, kB, vB);
    k_permRT<8,32,8><<<dim3(7,7,BB), 256, 0, stream>>>(qB, qA);
    k_permRT<8,32,8><<<dim3(7,7,BB), 256, 0, stream>>>(kB, kA);
    k_permRT<64,16,0><<<dim3(14,14,BB), 256, 0, stream>>>(vB, vA);

    k_scores<true ><<<BB*224, 256, 0, stream>>>(qA, kA, MH, ZH);
    k_scores<false><<<BB*224, 256, 0, stream>>>(qB, kB, MW, ZW);
    k_combine<<<(BB*NN + 255)/256, 256, 0, stream>>>(MH, ZH, MW, ZW, Mf, Zi);

    k_pv<true><<<BB*224, 256, 0, stream>>>(qA, kA, vA, Mf, Zi, gm, outA);

    k_mean<<<BB*CC, 256, 0, stream>>>(x, yMean);
    k_se2<<<1, 256, 0, stream>>>(yMean, W1, W2, y2);
    k_final<<<dim3(7,7,BB*CC), 256, 0, stream>>>(x, outA, y2, out);

    k_pv<false><<<BB*224, 256, 0, stream>>>(qB, kB, vB, Mf, Zi, gm, out);
}

// Round 3
// 235.006 us; speedup vs baseline: 3.7359x; 2.0823x over previous
//
#include <hip/hip_runtime.h>
#include <math.h>

#define CC 64
#define CQv 8
#define CRv 4
#define BB 4
#define RR 224
#define TT 224
#define NN (RR*TT)   // 50176

typedef __attribute__((ext_vector_type(8))) short short8;
typedef __attribute__((ext_vector_type(4))) float f32x4;

__device__ __forceinline__ f32x4 mfma_bf16(short8 a, short8 b, f32x4 c){
    return __builtin_amdgcn_mfma_f32_16x16x32_bf16(a, b, c, 0, 0, 0);
}

__device__ __forceinline__ ushort f2bf(float f){
    union { float f; unsigned u; } v; v.f = f;
    unsigned r = v.u + 0x7fffu + ((v.u >> 16) & 1u);
    return (ushort)(r >> 16);
}

// ---------------- K1: q,k,v 1x1 convs via MFMA, bf16 outputs ----------------
// qB[b][pos][8], kB[b][pos][8], vB[b][pos][64]  (bf16)
__global__ __launch_bounds__(256) void k_qkv(
    const float* __restrict__ x,
    const float* __restrict__ Wq, const float* __restrict__ bq,
    const float* __restrict__ Wk, const float* __restrict__ bk,
    const float* __restrict__ Wv, const float* __restrict__ bv,
    ushort* __restrict__ qB, ushort* __restrict__ kB, ushort* __restrict__ vB)
{
    const int tid = threadIdx.x;
    const int w = tid >> 6, l = tid & 63, l15 = l & 15, lg = l >> 4;
    const int blk = blockIdx.x;
    const int b = blk / 196, pb = blk - b*196;
    const int n0 = pb*256;
    const float* xb = x + (size_t)b*CC*NN;

    // A-fragments: W' rows (0-7 Wq, 8-15 Wk, 16-79 Wv), k-chunk = ks*32+lg*8
    short8 afr[5][2];
#pragma unroll
    for (int ot = 0; ot < 5; ++ot) {
        int oo = ot*16 + l15;
        const float* wr = (oo < 8) ? (Wq + oo*64)
                        : (oo < 16) ? (Wk + (oo-8)*64)
                                    : (Wv + (oo-16)*64);
#pragma unroll
        for (int ks = 0; ks < 2; ++ks) {
            const float* p = wr + ks*32 + lg*8;
            float4 w0 = *(const float4*)p, w1 = *(const float4*)(p+4);
            short8 f;
            f[0]=f2bf(w0.x); f[1]=f2bf(w0.y); f[2]=f2bf(w0.z); f[3]=f2bf(w0.w);
            f[4]=f2bf(w1.x); f[5]=f2bf(w1.y); f[6]=f2bf(w1.z); f[7]=f2bf(w1.w);
            afr[ot][ks] = f;
        }
    }
    f32x4 binit[5];
#pragma unroll
    for (int ot = 0; ot < 5; ++ot) {
        const float* bp;
        if (ot == 0) bp = (lg < 2) ? (bq + lg*4) : (bk + (lg-2)*4);
        else         bp = bv + (ot-1)*16 + lg*4;
        float4 bb4 = *(const float4*)bp;
        binit[ot] = (f32x4){bb4.x, bb4.y, bb4.z, bb4.w};
    }

#pragma unroll
    for (int j = 0; j < 4; ++j) {
        int n = n0 + (w*4 + j)*16 + l15;
        short8 bfr[2];
#pragma unroll
        for (int ks = 0; ks < 2; ++ks) {
            const float* xp = xb + (size_t)(ks*32 + lg*8)*NN + n;
            short8 f;
#pragma unroll
            for (int e = 0; e < 8; ++e) f[e] = f2bf(xp[(size_t)e*NN]);
            bfr[ks] = f;
        }
#pragma unroll
        for (int ot = 0; ot < 5; ++ot) {
            f32x4 acc = binit[ot];
            acc = mfma_bf16(afr[ot][0], bfr[0], acc);
            acc = mfma_bf16(afr[ot][1], bfr[1], acc);
            ushort4 pk;
            pk.x = f2bf(acc[0]); pk.y = f2bf(acc[1]);
            pk.z = f2bf(acc[2]); pk.w = f2bf(acc[3]);
            if (ot == 0) {
                ushort* dst = (lg < 2) ? (qB + ((size_t)b*NN + n)*8 + lg*4)
                                       : (kB + ((size_t)b*NN + n)*8 + (lg-2)*4);
                *(ushort4*)dst = pk;
            } else {
                int oc = (ot-1)*16 + lg*4;
                *(ushort4*)(vB + ((size_t)b*NN + n)*64 + oc) = pk;
            }
        }
    }
}

// ---------------- transpose q/k: [224][224] of 16B units per b ----------------
__global__ __launch_bounds__(256) void k_tq(const uint4* __restrict__ src, uint4* __restrict__ dst)
{
    __shared__ uint4 tile[32][33];
    int b = blockIdx.z;
    int t0 = blockIdx.x*32, r0 = blockIdx.y*32;
    int tx = threadIdx.x & 31, ty = threadIdx.x >> 5;
    const uint4* sp = src + (size_t)b*NN;
    uint4* dp = dst + (size_t)b*NN;
#pragma unroll
    for (int j = 0; j < 4; ++j) { int lr = ty + 8*j; tile[lr][tx] = sp[(size_t)(r0+lr)*224 + t0 + tx]; }
    __syncthreads();
#pragma unroll
    for (int j = 0; j < 4; ++j) { int lt = ty + 8*j; dp[(size_t)(t0+lt)*224 + r0 + tx] = tile[tx][lt]; }
}

// ---------------- transpose v: [224][224] of 128B cells (8x uint4) per b ----------------
__global__ __launch_bounds__(256) void k_tv(const uint4* __restrict__ src, uint4* __restrict__ dst)
{
    __shared__ uint4 lds[16*16*8];
    int b = blockIdx.z;
    int t0 = blockIdx.x*16, r0 = blockIdx.y*16;
    const uint4* sp = src + (size_t)b*NN*8;
    uint4* dp = dst + (size_t)b*NN*8;
#pragma unroll
    for (int j = 0; j < 8; ++j) {
        int u = j*256 + threadIdx.x;
        int sub = u & 7, lt = (u >> 3) & 15, lr = u >> 7;
        lds[u] = sp[((size_t)(r0+lr)*224 + (t0+lt))*8 + sub];
    }
    __syncthreads();
#pragma unroll
    for (int j = 0; j < 8; ++j) {
        int u = j*256 + threadIdx.x;
        int sub = u & 7, lr = (u >> 3) & 15, lt = u >> 7;
        dp[((size_t)(t0+lt)*224 + (r0+lr))*8 + sub] = lds[(lr*16 + lt)*8 + sub];
    }
}

// ---------------- scores via MFMA: per-(b,slice) row stats ----------------
template<bool HM>
__global__ __launch_bounds__(256) void k_scores(const ushort* __restrict__ Qsrc,
                                                const ushort* __restrict__ Ksrc,
                                                float* __restrict__ M, float* __restrict__ Z)
{
    __shared__ __align__(16) ushort Qh[224*8], Kh[224*8];
    __shared__ float red[4][224];
    __shared__ float Ms[224];
    const int tid = threadIdx.x;
    const int blk = blockIdx.x;
    const int b = blk / 224, o = blk - b*224;
    {
        const uint4* qp = (const uint4*)Qsrc + (size_t)blk*224;
        const uint4* kp = (const uint4*)Ksrc + (size_t)blk*224;
        if (tid < 224) { ((uint4*)Qh)[tid] = qp[tid]; ((uint4*)Kh)[tid] = kp[tid]; }
    }
    __syncthreads();
    const int w = tid >> 6, l = tid & 63, l15 = l & 15, lg = l >> 4;
    const short8 zfr = {0,0,0,0,0,0,0,0};
    const f32x4 zacc = {0.f,0.f,0.f,0.f};

    short8 kf[4];
#pragma unroll
    for (int j = 0; j < 4; ++j) {
        int ut = w + 4*j;
        kf[j] = (ut < 14 && lg == 0) ? *(const short8*)(Kh + (ut*16 + l15)*8) : zfr;
    }
    // pass 1: max
    for (int rt = 0; rt < 14; ++rt) {
        short8 qf = (lg == 0) ? *(const short8*)(Qh + (rt*16 + l15)*8) : zfr;
        float m = -1e30f;
#pragma unroll
        for (int j = 0; j < 4; ++j) {
            int ut = w + 4*j;
            if (ut < 14) {
                f32x4 e = mfma_bf16(kf[j], qf, zacc);
#pragma unroll
                for (int g = 0; g < 4; ++g) {
                    bool dg = HM && (ut*16 + lg*4 + g == rt*16 + l15);
                    m = dg ? m : fmaxf(m, e[g]);
                }
            }
        }
        m = fmaxf(m, __shfl_xor(m, 16));
        m = fmaxf(m, __shfl_xor(m, 32));
        if (lg == 0) red[w][rt*16 + l15] = m;
    }
    __syncthreads();
    if (tid < 224) Ms[tid] = fmaxf(fmaxf(red[0][tid], red[1][tid]), fmaxf(red[2][tid], red[3][tid]));
    __syncthreads();
    // pass 2: sum
    for (int rt = 0; rt < 14; ++rt) {
        short8 qf = (lg == 0) ? *(const short8*)(Qh + (rt*16 + l15)*8) : zfr;
        float mr = Ms[rt*16 + l15];
        float z = 0.f;
#pragma unroll
        for (int j = 0; j < 4; ++j) {
            int ut = w + 4*j;
            if (ut < 14) {
                f32x4 e = mfma_bf16(kf[j], qf, zacc);
#pragma unroll
                for (int g = 0; g < 4; ++g) {
                    bool dg = HM && (ut*16 + lg*4 + g == rt*16 + l15);
                    z += dg ? 0.f : __expf(e[g] - mr);
                }
            }
        }
        z += __shfl_xor(z, 16);
        z += __shfl_xor(z, 32);
        if (lg == 0) red[w][rt*16 + l15] = z;
    }
    __syncthreads();
    if (tid < 224) {
        float z = red[0][tid] + red[1][tid] + red[2][tid] + red[3][tid];
        size_t sidx = HM ? ((size_t)b*NN + (size_t)tid*TT + o)
                         : ((size_t)b*NN + (size_t)o*TT + tid);
        M[sidx] = Ms[tid];
        Z[sidx] = z;
    }
}

// ---------------- combine H/W stats ----------------
__global__ __launch_bounds__(256) void k_combine(const float* __restrict__ MH, const float* __restrict__ ZH,
                                                 const float* __restrict__ MW, const float* __restrict__ ZW,
                                                 float* __restrict__ Mf, float* __restrict__ Zi)
{
    int i = blockIdx.x*256 + threadIdx.x;
    if (i >= BB*NN) return;
    float mh = MH[i], mw = MW[i];
    float m = fmaxf(mh, mw);
    float z = ZH[i]*__expf(mh - m) + ZW[i]*__expf(mw - m);
    Mf[i] = m; Zi[i] = 1.f/z;
}

// ---------------- PV via MFMA ----------------
template<bool HM>
__global__ __launch_bounds__(256, 3) void k_pv(const ushort* __restrict__ Qsrc,
                                               const ushort* __restrict__ Ksrc,
                                               const ushort* __restrict__ Vsrc,
                                               const float* __restrict__ Mf, const float* __restrict__ Zi,
                                               const float* __restrict__ gammap,
                                               float* __restrict__ outp)
{
    __shared__ __align__(16) ushort Qh[224*8];
    __shared__ __align__(16) ushort Kh[224*8];
    __shared__ __align__(16) ushort Vt[64*224];  // bf16 [c][u], slot-swizzled
    __shared__ __align__(16) ushort Ah[32*224];  // bf16 [rl][u], slot-swizzled
    __shared__ float Ml[224], Zl[224];

    const int tid = threadIdx.x;
    const int blk = blockIdx.x;
    const int b = blk / 224, o = blk - b*224;
    const float g = gammap[0];

    {
        const uint4* qp = (const uint4*)Qsrc + (size_t)blk*224;
        const uint4* kp = (const uint4*)Ksrc + (size_t)blk*224;
        if (tid < 224) { ((uint4*)Qh)[tid] = qp[tid]; ((uint4*)Kh)[tid] = kp[tid]; }
    }
    // stage V transposed, swizzled: byte = c*448 + slot*16 + (u&7)*2,
    // slot = ((u>>3) + (c&7)) mod 28
    {
        const uint4* vp = (const uint4*)Vsrc + (size_t)blk*1792;
        char* vb = (char*)Vt;
        for (int i = tid; i < 1792; i += 256) {
            uint4 vv = vp[i];
            int u = i >> 3, c0 = (i & 7)*8;
            const ushort* pv = (const ushort*)&vv;
#pragma unroll
            for (int jj = 0; jj < 8; ++jj) {
                int c = c0 + jj;
                int slot = (u >> 3) + (c & 7); slot -= (slot >= 28) ? 28 : 0;
                *(ushort*)(vb + c*448 + slot*16 + (u & 7)*2) = pv[jj];
            }
        }
    }
    if (tid < 224) {
        size_t sidx = HM ? ((size_t)b*NN + (size_t)tid*TT + o)
                         : ((size_t)b*NN + (size_t)o*TT + tid);
        Ml[tid] = Mf[sidx];
        Zl[tid] = Zi[sidx];
    }
    __syncthreads();

    const int w = tid >> 6, l = tid & 63;
    const int l15 = l & 15, lg = l >> 4;

    short8 vfr[7];
    {
        const char* vb = (const char*)Vt;
        int c = w*16 + l15;
#pragma unroll
        for (int ks = 0; ks < 7; ++ks) {
            int u = ks*32 + lg*8;
            int slot = (u >> 3) + (c & 7); slot -= (slot >= 28) ? 28 : 0;
            vfr[ks] = *(const short8*)(vb + c*448 + slot*16);
        }
    }

    float* op;
    if (HM) op = outp + (size_t)blk*14336;                   // [c][r] slab
    else    op = outp + (size_t)b*CC*NN + (size_t)o*TT;      // + c*NN + t

    const short8 zfr = {0,0,0,0,0,0,0,0};
    const f32x4 zacc = {0.f,0.f,0.f,0.f};

    for (int ch = 0; ch < 7; ++ch) {
        const int r0 = ch*32;
        {
            short8 qf[2];
            float mreg[2], zreg[2];
#pragma unroll
            for (int rt = 0; rt < 2; ++rt) {
                int r = r0 + rt*16 + l15;
                qf[rt] = zfr;
                if (lg == 0) qf[rt] = *(const short8*)(Qh + r*8);
                mreg[rt] = Ml[r]; zreg[rt] = Zl[r];
            }
#pragma unroll
            for (int j = 0; j < 4; ++j) {
                int ut = w + 4*j;
                if (ut < 14) {
                    short8 kfv = zfr;
                    if (lg == 0) kfv = *(const short8*)(Kh + (ut*16 + l15)*8);
#pragma unroll
                    for (int rt = 0; rt < 2; ++rt) {
                        f32x4 e = mfma_bf16(kfv, qf[rt], zacc);
                        int ubase = ut*16 + lg*4;
                        int r = r0 + rt*16 + l15;
                        float att0 = __expf(e[0]-mreg[rt])*zreg[rt];
                        float att1 = __expf(e[1]-mreg[rt])*zreg[rt];
                        float att2 = __expf(e[2]-mreg[rt])*zreg[rt];
                        float att3 = __expf(e[3]-mreg[rt])*zreg[rt];
                        if (HM) {
                            if (ubase+0 == r) att0 = 0.f;
                            if (ubase+1 == r) att1 = 0.f;
                            if (ubase+2 == r) att2 = 0.f;
                            if (ubase+3 == r) att3 = 0.f;
                        }
                        unsigned lo = (unsigned)f2bf(att0) | ((unsigned)f2bf(att1) << 16);
                        unsigned hi = (unsigned)f2bf(att2) | ((unsigned)f2bf(att3) << 16);
                        int rl = rt*16 + l15;
                        int slot = (ubase >> 3) + (rl & 7); slot -= (slot >= 28) ? 28 : 0;
                        uint2 pk; pk.x = lo; pk.y = hi;
                        *(uint2*)((char*)Ah + rl*448 + slot*16 + (ubase & 7)*2) = pk;
                    }
                }
            }
        }
        __syncthreads();
        {
            const char* ab = (const char*)Ah;
#pragma unroll
            for (int rt = 0; rt < 2; ++rt) {
                f32x4 acc = zacc;
                int rl = rt*16 + l15;
#pragma unroll
                for (int ks = 0; ks < 7; ++ks) {
                    int u = ks*32 + lg*8;
                    int slot = (u >> 3) + (rl & 7); slot -= (slot >= 28) ? 28 : 0;
                    short8 af = *(const short8*)(ab + rl*448 + slot*16);
                    acc = mfma_bf16(vfr[ks], af, acc);
                }
                int c0 = w*16 + lg*4;
                int r = r0 + rt*16 + l15;
                if (HM) {
#pragma unroll
                    for (int reg = 0; reg < 4; ++reg)
                        op[(size_t)(c0+reg)*224 + r] = g*acc[reg];
                } else {
#pragma unroll
                    for (int reg = 0; reg < 4; ++reg) {
                        size_t a = (size_t)(c0+reg)*NN + r;
                        op[a] += g*acc[reg];
                    }
                }
            }
        }
        __syncthreads();
    }
}

// ---------------- SE branch ----------------
__global__ __launch_bounds__(256) void k_mean(const float* __restrict__ x, float* __restrict__ yMean)
{
    int bc = blockIdx.x;
    const float* xp = x + (size_t)bc*NN;
    float s = 0.f;
    for (int i = threadIdx.x; i < NN; i += 256) s += xp[i];
#pragma unroll
    for (int off = 32; off > 0; off >>= 1) s += __shfl_down(s, off);
    __shared__ float red[4];
    if ((threadIdx.x & 63) == 0) red[threadIdx.x >> 6] = s;
    __syncthreads();
    if (threadIdx.x == 0) yMean[bc] = (red[0]+red[1]+red[2]+red[3]) * (1.0f/NN);
}

__global__ __launch_bounds__(256) void k_se2(const float* __restrict__ yMean,
                                             const float* __restrict__ W1,
                                             const float* __restrict__ W2,
                                             float* __restrict__ y2)
{
    int tid = threadIdx.x;
    int b = tid >> 6, c = tid & 63;
    float h[CRv];
#pragma unroll
    for (int j = 0; j < CRv; ++j) {
        float s = 0.f;
#pragma unroll
        for (int cc = 0; cc < CC; ++cc) s += W1[j*CC + cc] * yMean[b*CC + cc];
        h[j] = fmaxf(s, 0.f);
    }
    float s2 = 0.f;
#pragma unroll
    for (int j = 0; j < CRv; ++j) s2 += W2[c*CRv + j] * h[j];
    y2[tid] = 1.f/(1.f + __expf(-s2));
}

// ---------------- final: out = x*(1+y2) + outA^T ----------------
__global__ __launch_bounds__(256) void k_final(const float* __restrict__ x,
                                               const float* __restrict__ outA,
                                               const float* __restrict__ y2,
                                               float* __restrict__ out)
{
    __shared__ float tile[32][33];
    int bc = blockIdx.z;
    int b = bc >> 6, c = bc & 63;
    int t0 = blockIdx.x*32, r0 = blockIdx.y*32;
    int tx = threadIdx.x & 31, ty = threadIdx.x >> 5;
    float scale = 1.f + y2[bc];
#pragma unroll
    for (int j = 0; j < 4; ++j) {
        int tl = ty + 8*j;
        tile[tl][tx] = outA[((size_t)(b*224 + t0 + tl)*64 + c)*224 + r0 + tx];
    }
    __syncthreads();
#pragma unroll
    for (int j = 0; j < 4; ++j) {
        int rl = ty + 8*j;
        size_t idx = ((size_t)bc*224 + (r0 + rl))*224 + t0 + tx;
        out[idx] = x[idx]*scale + tile[tx][rl];
    }
}

// ---------------- launcher ----------------
extern "C" void kernel_launch(void* const* d_in, const int* in_sizes, int n_in,
                              void* d_out, int out_size, void* d_ws, size_t ws_size,
                              hipStream_t stream)
{
    const float* x  = (const float*)d_in[0];
    const float* Wq = (const float*)d_in[1];
    const float* bq = (const float*)d_in[2];
    const float* Wk = (const float*)d_in[3];
    const float* bk = (const float*)d_in[4];
    const float* Wv = (const float*)d_in[5];
    const float* bv = (const float*)d_in[6];
    const float* gm = (const float*)d_in[7];
    const float* W1 = (const float*)d_in[8];
    const float* W2 = (const float*)d_in[9];
    float* out = (float*)d_out;

    constexpr size_t QSZ = (size_t)BB*NN*CQv;   // 1,605,632 bf16 elems
    constexpr size_t VSZ = (size_t)BB*NN*CC;    // 12,845,056 bf16 elems
    constexpr size_t SSZ = (size_t)BB*NN;       // 200,704 f32 elems

    ushort* qB = (ushort*)d_ws;
    ushort* kB = qB + QSZ;
    ushort* vB = kB + QSZ;
    ushort* qA = vB + VSZ;
    ushort* kA = qA + QSZ;
    ushort* vA = kA + QSZ;
    float*  MH = (float*)(vA + VSZ);
    float*  ZH = MH + SSZ;
    float*  MW = ZH + SSZ;
    float*  ZW = MW + SSZ;
    float*  Mf = ZW + SSZ;
    float*  Zi = Mf + SSZ;
    float*  outA  = Zi + SSZ;          // VSZ f32
    float*  yMean = outA + VSZ;
    float*  y2    = yMean + 256;
    (void)ws_size; (void)in_sizes; (void)n_in; (void)out_size;

    k_qkv<<<BB*196, 256, 0, stream>>>(x, Wq, bq, Wk, bk, Wv, bv, qB, kB, vB);
    k_tq<<<dim3(7,7,BB), 256, 0, stream>>>((const uint4*)qB, (uint4*)qA);
    k_tq<<<dim3(7,7,BB), 256, 0, stream>>>((const uint4*)kB, (uint4*)kA);
    k_tv<<<dim3(14,14,BB), 256, 0, stream>>>((const uint4*)vB, (uint4*)vA);

    k_scores<true ><<<BB*224, 256, 0, stream>>>(qA, kA, MH, ZH);
    k_scores<false><<<BB*224, 256, 0, stream>>>(qB, kB, MW, ZW);
    k_combine<<<(BB*NN + 255)/256, 256, 0, stream>>>(MH, ZH, MW, ZW, Mf, Zi);

    k_pv<true><<<BB*224, 256, 0, stream>>>(qA, kA, vA, Mf, Zi, gm, outA);

    k_mean<<<BB*CC, 256, 0, stream>>>(x, yMean);
    k_se2<<<1, 256, 0, stream>>>(yMean, W1, W2, y2);
    k_final<<<dim3(7,7,BB*CC), 256, 0, stream>>>(x, outA, y2, out);

    k_pv<false><<<BB*224, 256, 0, stream>>>(qB, kB, vB, Mf, Zi, gm, out);
}

// Round 4
// 187.135 us; speedup vs baseline: 4.6916x; 1.2558x over previous
//
#include <hip/hip_runtime.h>
#include <math.h>

#define CC 64
#define CQv 8
#define CRv 4
#define BB 4
#define RR 224
#define TT 224
#define NN (RR*TT)   // 50176

typedef __attribute__((ext_vector_type(8))) short short8;
typedef __attribute__((ext_vector_type(4))) float f32x4;

__device__ __forceinline__ f32x4 mfma_bf16(short8 a, short8 b, f32x4 c){
    return __builtin_amdgcn_mfma_f32_16x16x32_bf16(a, b, c, 0, 0, 0);
}

__device__ __forceinline__ ushort f2bf(float f){
    union { float f; unsigned u; } v; v.f = f;
    unsigned r = v.u + 0x7fffu + ((v.u >> 16) & 1u);
    return (ushort)(r >> 16);
}
__device__ __forceinline__ float bf2f(ushort u){
    return __uint_as_float((unsigned)u << 16);
}

// ---------------- zero yMean ----------------
__global__ __launch_bounds__(256) void k_zero(float* __restrict__ p)
{
    p[threadIdx.x] = 0.f;
}

// ---------------- K1: q,k,v 1x1 convs via MFMA + fused x-mean partials ----------------
// qB[b][pos][8], kB[b][pos][8], vB[b][pos][64]  (bf16); yMean accumulates channel sums
__global__ __launch_bounds__(256) void k_qkv(
    const float* __restrict__ x,
    const float* __restrict__ Wq, const float* __restrict__ bq,
    const float* __restrict__ Wk, const float* __restrict__ bk,
    const float* __restrict__ Wv, const float* __restrict__ bv,
    ushort* __restrict__ qB, ushort* __restrict__ kB, ushort* __restrict__ vB,
    float* __restrict__ yMean)
{
    const int tid = threadIdx.x;
    const int w = tid >> 6, l = tid & 63, l15 = l & 15, lg = l >> 4;
    const int blk = blockIdx.x;
    const int b = blk / 196, pb = blk - b*196;
    const int n0 = pb*256;
    const float* xb = x + (size_t)b*CC*NN;

    // A-fragments: W' rows (0-7 Wq, 8-15 Wk, 16-79 Wv), k-chunk = ks*32+lg*8
    short8 afr[5][2];
#pragma unroll
    for (int ot = 0; ot < 5; ++ot) {
        int oo = ot*16 + l15;
        const float* wr = (oo < 8) ? (Wq + oo*64)
                        : (oo < 16) ? (Wk + (oo-8)*64)
                                    : (Wv + (oo-16)*64);
#pragma unroll
        for (int ks = 0; ks < 2; ++ks) {
            const float* p = wr + ks*32 + lg*8;
            float4 w0 = *(const float4*)p, w1 = *(const float4*)(p+4);
            short8 f;
            f[0]=f2bf(w0.x); f[1]=f2bf(w0.y); f[2]=f2bf(w0.z); f[3]=f2bf(w0.w);
            f[4]=f2bf(w1.x); f[5]=f2bf(w1.y); f[6]=f2bf(w1.z); f[7]=f2bf(w1.w);
            afr[ot][ks] = f;
        }
    }
    f32x4 binit[5];
#pragma unroll
    for (int ot = 0; ot < 5; ++ot) {
        const float* bp;
        if (ot == 0) bp = (lg < 2) ? (bq + lg*4) : (bk + (lg-2)*4);
        else         bp = bv + (ot-1)*16 + lg*4;
        float4 bb4 = *(const float4*)bp;
        binit[ot] = (f32x4){bb4.x, bb4.y, bb4.z, bb4.w};
    }

    float msum[16];
#pragma unroll
    for (int i = 0; i < 16; ++i) msum[i] = 0.f;

#pragma unroll
    for (int j = 0; j < 4; ++j) {
        int n = n0 + (w*4 + j)*16 + l15;
        short8 bfr[2];
#pragma unroll
        for (int ks = 0; ks < 2; ++ks) {
            const float* xp = xb + (size_t)(ks*32 + lg*8)*NN + n;
            short8 f;
#pragma unroll
            for (int e = 0; e < 8; ++e) {
                float xv = xp[(size_t)e*NN];
                f[e] = f2bf(xv);
                msum[ks*8 + e] += xv;
            }
            bfr[ks] = f;
        }
#pragma unroll
        for (int ot = 0; ot < 5; ++ot) {
            f32x4 acc = binit[ot];
            acc = mfma_bf16(afr[ot][0], bfr[0], acc);
            acc = mfma_bf16(afr[ot][1], bfr[1], acc);
            ushort4 pk;
            pk.x = f2bf(acc[0]); pk.y = f2bf(acc[1]);
            pk.z = f2bf(acc[2]); pk.w = f2bf(acc[3]);
            if (ot == 0) {
                ushort* dst = (lg < 2) ? (qB + ((size_t)b*NN + n)*8 + lg*4)
                                       : (kB + ((size_t)b*NN + n)*8 + (lg-2)*4);
                *(ushort4*)dst = pk;
            } else {
                int oc = (ot-1)*16 + lg*4;
                *(ushort4*)(vB + ((size_t)b*NN + n)*64 + oc) = pk;
            }
        }
    }

    // ---- fused mean partials: reduce msum over the 16-lane (l15) group
#pragma unroll
    for (int i = 0; i < 16; ++i) {
        float s = msum[i];
        s += __shfl_xor(s, 1); s += __shfl_xor(s, 2);
        s += __shfl_xor(s, 4); s += __shfl_xor(s, 8);
        msum[i] = s;
    }
    __shared__ float msums[4][4][16];
    if (l15 == 0) {
#pragma unroll
        for (int i = 0; i < 16; ++i) msums[w][lg][i] = msum[i];
    }
    __syncthreads();
    if (tid < 64) {
        int c = tid;
        int lgi = (c >> 3) & 3, ii = (c >> 5)*8 + (c & 7);
        float t = msums[0][lgi][ii] + msums[1][lgi][ii] + msums[2][lgi][ii] + msums[3][lgi][ii];
        atomicAdd(&yMean[b*64 + c], t);
    }
}

// ---------------- transpose q/k: [224][224] of 16B units per b ----------------
__global__ __launch_bounds__(256) void k_tq(const uint4* __restrict__ src, uint4* __restrict__ dst)
{
    __shared__ uint4 tile[32][33];
    int b = blockIdx.z;
    int t0 = blockIdx.x*32, r0 = blockIdx.y*32;
    int tx = threadIdx.x & 31, ty = threadIdx.x >> 5;
    const uint4* sp = src + (size_t)b*NN;
    uint4* dp = dst + (size_t)b*NN;
#pragma unroll
    for (int j = 0; j < 4; ++j) { int lr = ty + 8*j; tile[lr][tx] = sp[(size_t)(r0+lr)*224 + t0 + tx]; }
    __syncthreads();
#pragma unroll
    for (int j = 0; j < 4; ++j) { int lt = ty + 8*j; dp[(size_t)(t0+lt)*224 + r0 + tx] = tile[tx][lt]; }
}

// ---------------- scores via MFMA: per-(b,slice) row stats ----------------
// HM: writes raw MH,ZH.  !HM: merges with MH/ZH -> Mf, Zi=1/z.
template<bool HM>
__global__ __launch_bounds__(256) void k_scores(const ushort* __restrict__ Qsrc,
                                                const ushort* __restrict__ Ksrc,
                                                const float* __restrict__ MHp,
                                                const float* __restrict__ ZHp,
                                                float* __restrict__ M, float* __restrict__ Z)
{
    __shared__ __align__(16) ushort Qh[224*8], Kh[224*8];
    __shared__ float red[4][224];
    __shared__ float Ms[224];
    const int tid = threadIdx.x;
    const int blk = blockIdx.x;
    const int b = blk / 224, o = blk - b*224;
    {
        const uint4* qp = (const uint4*)Qsrc + (size_t)blk*224;
        const uint4* kp = (const uint4*)Ksrc + (size_t)blk*224;
        if (tid < 224) { ((uint4*)Qh)[tid] = qp[tid]; ((uint4*)Kh)[tid] = kp[tid]; }
    }
    __syncthreads();
    const int w = tid >> 6, l = tid & 63, l15 = l & 15, lg = l >> 4;
    const short8 zfr = {0,0,0,0,0,0,0,0};
    const f32x4 zacc = {0.f,0.f,0.f,0.f};

    short8 kf[4];
#pragma unroll
    for (int j = 0; j < 4; ++j) {
        int ut = w + 4*j;
        kf[j] = (ut < 14 && lg == 0) ? *(const short8*)(Kh + (ut*16 + l15)*8) : zfr;
    }
    // pass 1: max
    for (int rt = 0; rt < 14; ++rt) {
        short8 qf = (lg == 0) ? *(const short8*)(Qh + (rt*16 + l15)*8) : zfr;
        float m = -1e30f;
#pragma unroll
        for (int j = 0; j < 4; ++j) {
            int ut = w + 4*j;
            if (ut < 14) {
                f32x4 e = mfma_bf16(kf[j], qf, zacc);
#pragma unroll
                for (int g = 0; g < 4; ++g) {
                    bool dg = HM && (ut*16 + lg*4 + g == rt*16 + l15);
                    m = dg ? m : fmaxf(m, e[g]);
                }
            }
        }
        m = fmaxf(m, __shfl_xor(m, 16));
        m = fmaxf(m, __shfl_xor(m, 32));
        if (lg == 0) red[w][rt*16 + l15] = m;
    }
    __syncthreads();
    if (tid < 224) Ms[tid] = fmaxf(fmaxf(red[0][tid], red[1][tid]), fmaxf(red[2][tid], red[3][tid]));
    __syncthreads();
    // pass 2: sum
    for (int rt = 0; rt < 14; ++rt) {
        short8 qf = (lg == 0) ? *(const short8*)(Qh + (rt*16 + l15)*8) : zfr;
        float mr = Ms[rt*16 + l15];
        float z = 0.f;
#pragma unroll
        for (int j = 0; j < 4; ++j) {
            int ut = w + 4*j;
            if (ut < 14) {
                f32x4 e = mfma_bf16(kf[j], qf, zacc);
#pragma unroll
                for (int g = 0; g < 4; ++g) {
                    bool dg = HM && (ut*16 + lg*4 + g == rt*16 + l15);
                    z += dg ? 0.f : __expf(e[g] - mr);
                }
            }
        }
        z += __shfl_xor(z, 16);
        z += __shfl_xor(z, 32);
        if (lg == 0) red[w][rt*16 + l15] = z;
    }
    __syncthreads();
    if (tid < 224) {
        float z = red[0][tid] + red[1][tid] + red[2][tid] + red[3][tid];
        if (HM) {
            size_t sidx = (size_t)b*NN + (size_t)tid*TT + o;
            M[sidx] = Ms[tid];
            Z[sidx] = z;
        } else {
            size_t sidx = (size_t)b*NN + (size_t)o*TT + tid;
            float mh = MHp[sidx], zh = ZHp[sidx];
            float m = fmaxf(Ms[tid], mh);
            float zz = z*__expf(Ms[tid] - m) + zh*__expf(mh - m);
            M[sidx] = m;
            Z[sidx] = 1.f/zz;
        }
    }
}

// ---------------- PV via MFMA: both paths write a bf16 [64][224] slab ----------------
// HM: outA[b][t=o][c][r]; !HM: outB[b][r=o][c][t]
template<bool HM>
__global__ __launch_bounds__(256, 3) void k_pv(const ushort* __restrict__ Qsrc,
                                               const ushort* __restrict__ Ksrc,
                                               const ushort* __restrict__ Vsrc,
                                               const float* __restrict__ Mf, const float* __restrict__ Zi,
                                               const float* __restrict__ gammap,
                                               ushort* __restrict__ outp)
{
    __shared__ __align__(16) ushort Qh[224*8];
    __shared__ __align__(16) ushort Kh[224*8];
    __shared__ __align__(16) ushort Vt[64*224];  // bf16 [c][u], slot-swizzled
    __shared__ __align__(16) ushort Ah[32*224];  // bf16 [rl][u], slot-swizzled
    __shared__ float Ml[224], Zl[224];

    const int tid = threadIdx.x;
    const int blk = blockIdx.x;
    const int b = blk / 224, o = blk - b*224;
    const float g = gammap[0];

    {
        const uint4* qp = (const uint4*)Qsrc + (size_t)blk*224;
        const uint4* kp = (const uint4*)Ksrc + (size_t)blk*224;
        if (tid < 224) { ((uint4*)Qh)[tid] = qp[tid]; ((uint4*)Kh)[tid] = kp[tid]; }
    }
    // stage V transposed, swizzled: byte = c*448 + slot*16 + (u&7)*2,
    // slot = ((u>>3) + (c&7)) mod 28.  HM gathers 128B rows from vB.
    {
        const uint4* vbase = (const uint4*)Vsrc;
        char* vb = (char*)Vt;
        for (int i = tid; i < 1792; i += 256) {
            int u = i >> 3, sub = i & 7;
            size_t vidx = HM ? ((size_t)b*NN + (size_t)u*224 + o)*8 + sub
                             : ((size_t)blk*224 + (size_t)u)*8 + sub;
            uint4 vv = vbase[vidx];
            int c0 = sub*8;
            const ushort* pv = (const ushort*)&vv;
#pragma unroll
            for (int jj = 0; jj < 8; ++jj) {
                int c = c0 + jj;
                int slot = (u >> 3) + (c & 7); slot -= (slot >= 28) ? 28 : 0;
                *(ushort*)(vb + c*448 + slot*16 + (u & 7)*2) = pv[jj];
            }
        }
    }
    if (tid < 224) {
        size_t sidx = HM ? ((size_t)b*NN + (size_t)tid*TT + o)
                         : ((size_t)b*NN + (size_t)o*TT + tid);
        Ml[tid] = Mf[sidx];
        Zl[tid] = Zi[sidx];
    }
    __syncthreads();

    const int w = tid >> 6, l = tid & 63;
    const int l15 = l & 15, lg = l >> 4;

    short8 vfr[7];
    {
        const char* vb = (const char*)Vt;
        int c = w*16 + l15;
#pragma unroll
        for (int ks = 0; ks < 7; ++ks) {
            int u = ks*32 + lg*8;
            int slot = (u >> 3) + (c & 7); slot -= (slot >= 28) ? 28 : 0;
            vfr[ks] = *(const short8*)(vb + c*448 + slot*16);
        }
    }

    ushort* op = outp + (size_t)blk*14336;   // [c][pos] slab

    const short8 zfr = {0,0,0,0,0,0,0,0};
    const f32x4 zacc = {0.f,0.f,0.f,0.f};

    for (int ch = 0; ch < 7; ++ch) {
        const int r0 = ch*32;
        {
            short8 qf[2];
            float mreg[2], zreg[2];
#pragma unroll
            for (int rt = 0; rt < 2; ++rt) {
                int r = r0 + rt*16 + l15;
                qf[rt] = zfr;
                if (lg == 0) qf[rt] = *(const short8*)(Qh + r*8);
                mreg[rt] = Ml[r]; zreg[rt] = Zl[r];
            }
#pragma unroll
            for (int j = 0; j < 4; ++j) {
                int ut = w + 4*j;
                if (ut < 14) {
                    short8 kfv = zfr;
                    if (lg == 0) kfv = *(const short8*)(Kh + (ut*16 + l15)*8);
#pragma unroll
                    for (int rt = 0; rt < 2; ++rt) {
                        f32x4 e = mfma_bf16(kfv, qf[rt], zacc);
                        int ubase = ut*16 + lg*4;
                        int r = r0 + rt*16 + l15;
                        float att0 = __expf(e[0]-mreg[rt])*zreg[rt];
                        float att1 = __expf(e[1]-mreg[rt])*zreg[rt];
                        float att2 = __expf(e[2]-mreg[rt])*zreg[rt];
                        float att3 = __expf(e[3]-mreg[rt])*zreg[rt];
                        if (HM) {
                            if (ubase+0 == r) att0 = 0.f;
                            if (ubase+1 == r) att1 = 0.f;
                            if (ubase+2 == r) att2 = 0.f;
                            if (ubase+3 == r) att3 = 0.f;
                        }
                        unsigned lo = (unsigned)f2bf(att0) | ((unsigned)f2bf(att1) << 16);
                        unsigned hi = (unsigned)f2bf(att2) | ((unsigned)f2bf(att3) << 16);
                        int rl = rt*16 + l15;
                        int slot = (ubase >> 3) + (rl & 7); slot -= (slot >= 28) ? 28 : 0;
                        uint2 pk; pk.x = lo; pk.y = hi;
                        *(uint2*)((char*)Ah + rl*448 + slot*16 + (ubase & 7)*2) = pk;
                    }
                }
            }
        }
        __syncthreads();
        {
            const char* ab = (const char*)Ah;
#pragma unroll
            for (int rt = 0; rt < 2; ++rt) {
                f32x4 acc = zacc;
                int rl = rt*16 + l15;
#pragma unroll
                for (int ks = 0; ks < 7; ++ks) {
                    int u = ks*32 + lg*8;
                    int slot = (u >> 3) + (rl & 7); slot -= (slot >= 28) ? 28 : 0;
                    short8 af = *(const short8*)(ab + rl*448 + slot*16);
                    acc = mfma_bf16(vfr[ks], af, acc);
                }
                int c0 = w*16 + lg*4;
                int r = r0 + rt*16 + l15;
#pragma unroll
                for (int reg = 0; reg < 4; ++reg)
                    op[(size_t)(c0+reg)*224 + r] = f2bf(g*acc[reg]);
            }
        }
        __syncthreads();
    }
}

// ---------------- SE stage 2 ----------------
__global__ __launch_bounds__(256) void k_se2(const float* __restrict__ yMean,
                                             const float* __restrict__ W1,
                                             const float* __restrict__ W2,
                                             float* __restrict__ y2)
{
    int tid = threadIdx.x;
    int b = tid >> 6, c = tid & 63;
    float h[CRv];
#pragma unroll
    for (int j = 0; j < CRv; ++j) {
        float s = 0.f;
#pragma unroll
        for (int cc = 0; cc < CC; ++cc) s += W1[j*CC + cc] * yMean[b*CC + cc];
        h[j] = fmaxf(s * (1.0f/NN), 0.f);
    }
    float s2 = 0.f;
#pragma unroll
    for (int j = 0; j < CRv; ++j) s2 += W2[c*CRv + j] * h[j];
    y2[tid] = 1.f/(1.f + __expf(-s2));
}

// ---------------- final: out = x*(1+y2) + outA^T + outB ----------------
__global__ __launch_bounds__(256) void k_final(const float* __restrict__ x,
                                               const ushort* __restrict__ outA,
                                               const ushort* __restrict__ outB,
                                               const float* __restrict__ y2,
                                               float* __restrict__ out)
{
    __shared__ ushort tile[32][34];
    int bc = blockIdx.z;
    int b = bc >> 6, c = bc & 63;
    int t0 = blockIdx.x*32, r0 = blockIdx.y*32;
    int tx = threadIdx.x & 31, ty = threadIdx.x >> 5;
    float scale = 1.f + y2[bc];
#pragma unroll
    for (int j = 0; j < 4; ++j) {
        int tl = ty + 8*j;
        tile[tl][tx] = outA[((size_t)(b*224 + t0 + tl)*64 + c)*224 + r0 + tx];
    }
    __syncthreads();
#pragma unroll
    for (int j = 0; j < 4; ++j) {
        int rl = ty + 8*j;
        size_t idx = ((size_t)bc*224 + (r0 + rl))*224 + t0 + tx;
        float a = bf2f(tile[tx][rl]);
        float wv = bf2f(outB[((size_t)(b*224 + r0 + rl)*64 + c)*224 + t0 + tx]);
        out[idx] = x[idx]*scale + a + wv;
    }
}

// ---------------- launcher ----------------
extern "C" void kernel_launch(void* const* d_in, const int* in_sizes, int n_in,
                              void* d_out, int out_size, void* d_ws, size_t ws_size,
                              hipStream_t stream)
{
    const float* x  = (const float*)d_in[0];
    const float* Wq = (const float*)d_in[1];
    const float* bq = (const float*)d_in[2];
    const float* Wk = (const float*)d_in[3];
    const float* bk = (const float*)d_in[4];
    const float* Wv = (const float*)d_in[5];
    const float* bv = (const float*)d_in[6];
    const float* gm = (const float*)d_in[7];
    const float* W1 = (const float*)d_in[8];
    const float* W2 = (const float*)d_in[9];
    float* out = (float*)d_out;

    constexpr size_t QSZ = (size_t)BB*NN*CQv;   // bf16 elems
    constexpr size_t VSZ = (size_t)BB*NN*CC;    // bf16 elems
    constexpr size_t SSZ = (size_t)BB*NN;       // f32 elems

    ushort* qB = (ushort*)d_ws;
    ushort* kB = qB + QSZ;
    ushort* vB = kB + QSZ;
    ushort* qA = vB + VSZ;
    ushort* kA = qA + QSZ;
    ushort* outA = kA + QSZ;
    ushort* outB = outA + VSZ;
    float*  MH = (float*)(outB + VSZ);
    float*  ZH = MH + SSZ;
    float*  Mf = ZH + SSZ;
    float*  Zi = Mf + SSZ;
    float*  yMean = Zi + SSZ;
    float*  y2    = yMean + 256;
    (void)ws_size; (void)in_sizes; (void)n_in; (void)out_size;

    k_zero<<<1, 256, 0, stream>>>(yMean);
    k_qkv<<<BB*196, 256, 0, stream>>>(x, Wq, bq, Wk, bk, Wv, bv, qB, kB, vB, yMean);
    k_tq<<<dim3(7,7,BB), 256, 0, stream>>>((const uint4*)qB, (uint4*)qA);
    k_tq<<<dim3(7,7,BB), 256, 0, stream>>>((const uint4*)kB, (uint4*)kA);

    k_scores<true ><<<BB*224, 256, 0, stream>>>(qA, kA, nullptr, nullptr, MH, ZH);
    k_scores<false><<<BB*224, 256, 0, stream>>>(qB, kB, MH, ZH, Mf, Zi);

    k_pv<true ><<<BB*224, 256, 0, stream>>>(qA, kA, vB, Mf, Zi, gm, outA);
    k_se2<<<1, 256, 0, stream>>>(yMean, W1, W2, y2);
    k_pv<false><<<BB*224, 256, 0, stream>>>(qB, kB, vB, Mf, Zi, gm, outB);

    k_final<<<dim3(7,7,BB*CC), 256, 0, stream>>>(x, outA, outB, y2, out);
}

// Round 5
// 162.923 us; speedup vs baseline: 5.3888x; 1.1486x over previous
//
#include <hip/hip_runtime.h>
#include <math.h>

#define CC 64
#define CQv 8
#define CRv 4
#define BB 4
#define RR 224
#define TT 224
#define NN (RR*TT)   // 50176
#define LOG2E 1.4426950408889634f

typedef __attribute__((ext_vector_type(8))) short short8;
typedef __attribute__((ext_vector_type(4))) float f32x4;

__device__ __forceinline__ f32x4 mfma_bf16(short8 a, short8 b, f32x4 c){
    return __builtin_amdgcn_mfma_f32_16x16x32_bf16(a, b, c, 0, 0, 0);
}

__device__ __forceinline__ ushort f2bf(float f){
    union { float f; unsigned u; } v; v.f = f;
    unsigned r = v.u + 0x7fffu + ((v.u >> 16) & 1u);
    return (ushort)(r >> 16);
}
__device__ __forceinline__ float bf2f(ushort u){
    return __uint_as_float((unsigned)u << 16);
}
// pack two f32 as truncated bf16 pair: [lo=a, hi=b]
__device__ __forceinline__ unsigned packbf(float a, float b){
    return __builtin_amdgcn_perm(__float_as_uint(b), __float_as_uint(a), 0x07060302u);
}

// ---------------- zero yMean ----------------
__global__ __launch_bounds__(256) void k_zero(float* __restrict__ p)
{
    p[threadIdx.x] = 0.f;
}

// ---------------- K1: q,k,v 1x1 convs via MFMA + fused x-mean partials ----------------
// qB[b][pos][8], kB[b][pos][8] (k pre-scaled by log2e), vB[b][pos][64]  (bf16)
__global__ __launch_bounds__(256) void k_qkv(
    const float* __restrict__ x,
    const float* __restrict__ Wq, const float* __restrict__ bq,
    const float* __restrict__ Wk, const float* __restrict__ bk,
    const float* __restrict__ Wv, const float* __restrict__ bv,
    ushort* __restrict__ qB, ushort* __restrict__ kB, ushort* __restrict__ vB,
    float* __restrict__ yMean)
{
    const int tid = threadIdx.x;
    const int w = tid >> 6, l = tid & 63, l15 = l & 15, lg = l >> 4;
    const int blk = blockIdx.x;
    const int b = blk / 196, pb = blk - b*196;
    const int n0 = pb*256;
    const float* xb = x + (size_t)b*CC*NN;

    short8 afr[5][2];
#pragma unroll
    for (int ot = 0; ot < 5; ++ot) {
        int oo = ot*16 + l15;
        const float* wr = (oo < 8) ? (Wq + oo*64)
                        : (oo < 16) ? (Wk + (oo-8)*64)
                                    : (Wv + (oo-16)*64);
        float scl = (oo >= 8 && oo < 16) ? LOG2E : 1.0f;
#pragma unroll
        for (int ks = 0; ks < 2; ++ks) {
            const float* p = wr + ks*32 + lg*8;
            float4 w0 = *(const float4*)p, w1 = *(const float4*)(p+4);
            short8 f;
            f[0]=f2bf(w0.x*scl); f[1]=f2bf(w0.y*scl); f[2]=f2bf(w0.z*scl); f[3]=f2bf(w0.w*scl);
            f[4]=f2bf(w1.x*scl); f[5]=f2bf(w1.y*scl); f[6]=f2bf(w1.z*scl); f[7]=f2bf(w1.w*scl);
            afr[ot][ks] = f;
        }
    }
    f32x4 binit[5];
#pragma unroll
    for (int ot = 0; ot < 5; ++ot) {
        const float* bp;
        float scl = 1.0f;
        if (ot == 0) { bp = (lg < 2) ? (bq + lg*4) : (bk + (lg-2)*4); if (lg >= 2) scl = LOG2E; }
        else           bp = bv + (ot-1)*16 + lg*4;
        float4 bb4 = *(const float4*)bp;
        binit[ot] = (f32x4){bb4.x*scl, bb4.y*scl, bb4.z*scl, bb4.w*scl};
    }

    float msum[16];
#pragma unroll
    for (int i = 0; i < 16; ++i) msum[i] = 0.f;

#pragma unroll
    for (int j = 0; j < 4; ++j) {
        int n = n0 + (w*4 + j)*16 + l15;
        short8 bfr[2];
#pragma unroll
        for (int ks = 0; ks < 2; ++ks) {
            const float* xp = xb + (size_t)(ks*32 + lg*8)*NN + n;
            short8 f;
#pragma unroll
            for (int e = 0; e < 8; ++e) {
                float xv = xp[(size_t)e*NN];
                f[e] = f2bf(xv);
                msum[ks*8 + e] += xv;
            }
            bfr[ks] = f;
        }
#pragma unroll
        for (int ot = 0; ot < 5; ++ot) {
            f32x4 acc = binit[ot];
            acc = mfma_bf16(afr[ot][0], bfr[0], acc);
            acc = mfma_bf16(afr[ot][1], bfr[1], acc);
            ushort4 pk;
            pk.x = f2bf(acc[0]); pk.y = f2bf(acc[1]);
            pk.z = f2bf(acc[2]); pk.w = f2bf(acc[3]);
            if (ot == 0) {
                ushort* dst = (lg < 2) ? (qB + ((size_t)b*NN + n)*8 + lg*4)
                                       : (kB + ((size_t)b*NN + n)*8 + (lg-2)*4);
                *(ushort4*)dst = pk;
            } else {
                int oc = (ot-1)*16 + lg*4;
                *(ushort4*)(vB + ((size_t)b*NN + n)*64 + oc) = pk;
            }
        }
    }

#pragma unroll
    for (int i = 0; i < 16; ++i) {
        float s = msum[i];
        s += __shfl_xor(s, 1); s += __shfl_xor(s, 2);
        s += __shfl_xor(s, 4); s += __shfl_xor(s, 8);
        msum[i] = s;
    }
    __shared__ float msums[4][4][16];
    if (l15 == 0) {
#pragma unroll
        for (int i = 0; i < 16; ++i) msums[w][lg][i] = msum[i];
    }
    __syncthreads();
    if (tid < 64) {
        int c = tid;
        int lgi = (c >> 3) & 3, ii = (c >> 5)*8 + (c & 7);
        float t = msums[0][lgi][ii] + msums[1][lgi][ii] + msums[2][lgi][ii] + msums[3][lgi][ii];
        atomicAdd(&yMean[b*64 + c], t);
    }
}

// ---------------- transpose q/k: [224][224] of 16B units per b (both in one) ----------------
__global__ __launch_bounds__(256) void k_tq(const uint4* __restrict__ qs, const uint4* __restrict__ ks,
                                            uint4* __restrict__ qd, uint4* __restrict__ kd)
{
    __shared__ uint4 tile[32][33];
    int z = blockIdx.z;
    int b = z & 3;
    const uint4* sp = ((z >= 4) ? ks : qs) + (size_t)b*NN;
    uint4*       dp = ((z >= 4) ? kd : qd) + (size_t)b*NN;
    int t0 = blockIdx.x*32, r0 = blockIdx.y*32;
    int tx = threadIdx.x & 31, ty = threadIdx.x >> 5;
#pragma unroll
    for (int j = 0; j < 4; ++j) { int lr = ty + 8*j; tile[lr][tx] = sp[(size_t)(r0+lr)*224 + t0 + tx]; }
    __syncthreads();
#pragma unroll
    for (int j = 0; j < 4; ++j) { int lt = ty + 8*j; dp[(size_t)(t0+lt)*224 + r0 + tx] = tile[tx][lt]; }
}

// ---------------- scores via MFMA: single dispatch, raw M/Z for both paths ----------------
__global__ __launch_bounds__(256) void k_scores(const ushort* __restrict__ qA, const ushort* __restrict__ kA,
                                                const ushort* __restrict__ qB, const ushort* __restrict__ kB,
                                                float* __restrict__ MH, float* __restrict__ ZH,
                                                float* __restrict__ MW, float* __restrict__ ZW)
{
    __shared__ __align__(16) ushort Qh[224*8];
    __shared__ float red[4][224];
    __shared__ float Ms[224];
    const int tid = threadIdx.x;
    const int bid = blockIdx.x;
    const bool HM = bid < BB*224;
    const int blk = HM ? bid : bid - BB*224;
    const int b = blk / 224, o = blk - b*224;
    const ushort* Qsrc = (HM ? qA : qB) + (size_t)blk*1792;
    const ushort* Ksrc = (HM ? kA : kB) + (size_t)blk*1792;
    if (tid < 224) ((uint4*)Qh)[tid] = ((const uint4*)Qsrc)[tid];
    __syncthreads();
    const int w = tid >> 6, l = tid & 63, l15 = l & 15, lg = l >> 4;
    const short8 zfr = {0,0,0,0,0,0,0,0};
    const f32x4 zacc = {0.f,0.f,0.f,0.f};

    short8 kf[4];
#pragma unroll
    for (int j = 0; j < 4; ++j) {
        int ut = w + 4*j;
        kf[j] = (ut < 14 && lg == 0) ? *(const short8*)(Ksrc + (size_t)(ut*16 + l15)*8) : zfr;
    }
    // pass 1: max
    for (int rt = 0; rt < 14; ++rt) {
        short8 qf = (lg == 0) ? *(const short8*)(Qh + (rt*16 + l15)*8) : zfr;
        float m = -1e30f;
#pragma unroll
        for (int j = 0; j < 4; ++j) {
            int ut = w + 4*j;
            if (ut < 14) {
                f32x4 e = mfma_bf16(kf[j], qf, zacc);
#pragma unroll
                for (int g = 0; g < 4; ++g) {
                    bool dg = HM && (ut*16 + lg*4 + g == rt*16 + l15);
                    m = dg ? m : fmaxf(m, e[g]);
                }
            }
        }
        m = fmaxf(m, __shfl_xor(m, 16));
        m = fmaxf(m, __shfl_xor(m, 32));
        if (lg == 0) red[w][rt*16 + l15] = m;
    }
    __syncthreads();
    if (tid < 224) Ms[tid] = fmaxf(fmaxf(red[0][tid], red[1][tid]), fmaxf(red[2][tid], red[3][tid]));
    __syncthreads();
    // pass 2: sum (log2 domain)
    for (int rt = 0; rt < 14; ++rt) {
        short8 qf = (lg == 0) ? *(const short8*)(Qh + (rt*16 + l15)*8) : zfr;
        float mr = Ms[rt*16 + l15];
        float z = 0.f;
#pragma unroll
        for (int j = 0; j < 4; ++j) {
            int ut = w + 4*j;
            if (ut < 14) {
                f32x4 e = mfma_bf16(kf[j], qf, zacc);
#pragma unroll
                for (int g = 0; g < 4; ++g) {
                    bool dg = HM && (ut*16 + lg*4 + g == rt*16 + l15);
                    z += dg ? 0.f : __builtin_amdgcn_exp2f(e[g] - mr);
                }
            }
        }
        z += __shfl_xor(z, 16);
        z += __shfl_xor(z, 32);
        if (lg == 0) red[w][rt*16 + l15] = z;
    }
    __syncthreads();
    if (tid < 224) {
        float z = red[0][tid] + red[1][tid] + red[2][tid] + red[3][tid];
        if (HM) {
            size_t sidx = (size_t)b*NN + (size_t)tid*TT + o;
            MH[sidx] = Ms[tid]; ZH[sidx] = z;
        } else {
            size_t sidx = (size_t)b*NN + (size_t)o*TT + tid;
            MW[sidx] = Ms[tid]; ZW[sidx] = z;
        }
    }
}

// ---------------- combine H/W stats ----------------
__global__ __launch_bounds__(256) void k_combine(const float* __restrict__ MH, const float* __restrict__ ZH,
                                                 const float* __restrict__ MW, const float* __restrict__ ZW,
                                                 float* __restrict__ Mf, float* __restrict__ Zi)
{
    int i = blockIdx.x*256 + threadIdx.x;
    if (i >= BB*NN) return;
    float mh = MH[i], mw = MW[i];
    float m = fmaxf(mh, mw);
    float z = ZH[i]*__builtin_amdgcn_exp2f(mh - m) + ZW[i]*__builtin_amdgcn_exp2f(mw - m);
    Mf[i] = m; Zi[i] = 1.f/z;
}

// ---------------- PV via MFMA: single dispatch, both paths ----------------
__global__ __launch_bounds__(256, 3) void k_pv(const ushort* __restrict__ qA, const ushort* __restrict__ kA,
                                               const ushort* __restrict__ qB, const ushort* __restrict__ kB,
                                               const ushort* __restrict__ vB,
                                               const float* __restrict__ Mf, const float* __restrict__ Zi,
                                               const float* __restrict__ gammap,
                                               ushort* __restrict__ outA, ushort* __restrict__ outB)
{
    __shared__ __align__(16) ushort Vt[64*224];  // bf16 [c][u], slot-swizzled
    __shared__ __align__(16) ushort Ah[32*224];  // bf16 [rl][u], slot-swizzled
    __shared__ float Ml[224], Zl[224];

    const int tid = threadIdx.x;
    const int bid = blockIdx.x;
    const bool HM = bid < BB*224;
    const int blk = HM ? bid : bid - BB*224;
    const int b = blk / 224, o = blk - b*224;
    const float g = gammap[0];
    const ushort* Qsrc = (HM ? qA : qB) + (size_t)blk*1792;
    const ushort* Ksrc = (HM ? kA : kB) + (size_t)blk*1792;
    ushort* op = (HM ? outA : outB) + (size_t)blk*14336;

    // ---- stage V^T: load 4u x 8c register block, write 8x ds_write_b64
    // layout: byte = c*448 + slot*16 + (u&7)*2, slot = ((u>>3)+c) mod 28
    {
        const uint4* vbase = (const uint4*)vB;
        for (int gi = tid; gi < 448; gi += 256) {
            int ublk = gi >> 3, sub = gi & 7;
            int u0 = ublk << 2;
            size_t base, stride;
            if (HM) { base = ((size_t)b*NN + (size_t)u0*224 + o)*8 + sub; stride = 1792; }
            else    { base = ((size_t)blk*224 + u0)*8 + sub;              stride = 8;    }
            uint4 r0 = vbase[base], r1 = vbase[base+stride], r2 = vbase[base+2*stride], r3 = vbase[base+3*stride];
            const ushort* p0 = (const ushort*)&r0;
            const ushort* p1 = (const ushort*)&r1;
            const ushort* p2 = (const ushort*)&r2;
            const ushort* p3 = (const ushort*)&r3;
            int half = (ublk & 1) * 8;
            int sbase = (ublk >> 1) + sub*8;
#pragma unroll
            for (int j = 0; j < 8; ++j) {
                int c = sub*8 + j;
                int s = (sbase + j) % 28;
                ushort4 col; col.x = p0[j]; col.y = p1[j]; col.z = p2[j]; col.w = p3[j];
                *(ushort4*)((char*)Vt + c*448 + s*16 + half) = col;
            }
        }
    }
    if (tid < 224) {
        size_t sidx = HM ? ((size_t)b*NN + (size_t)tid*TT + o)
                         : ((size_t)b*NN + (size_t)o*TT + tid);
        Ml[tid] = Mf[sidx];
        Zl[tid] = Zi[sidx];
    }
    __syncthreads();

    const int w = tid >> 6, l = tid & 63;
    const int l15 = l & 15, lg = l >> 4;
    const short8 zfr = {0,0,0,0,0,0,0,0};
    const f32x4 zacc = {0.f,0.f,0.f,0.f};

    // hoisted V^T fragments (A-operand rows = channels)
    short8 vfr[7];
    {
        int c = w*16 + l15;
#pragma unroll
        for (int ks = 0; ks < 7; ++ks) {
            int s = (ks*4 + lg + c) % 28;
            vfr[ks] = *(const short8*)((const char*)Vt + c*448 + s*16);
        }
    }
    // hoisted K fragments (same tiles for every chunk)
    short8 kf[4];
#pragma unroll
    for (int j = 0; j < 4; ++j) {
        int ut = w + 4*j;
        kf[j] = (ut < 14 && lg == 0) ? *(const short8*)(Ksrc + (size_t)(ut*16 + l15)*8) : zfr;
    }

    for (int ch = 0; ch < 7; ++ch) {
        const int r0 = ch*32;
        {   // score phase: att = exp2(e - m), truncated bf16, perm-packed
            short8 qf[2];
            float mreg[2];
#pragma unroll
            for (int rt = 0; rt < 2; ++rt) {
                int r = r0 + rt*16 + l15;
                qf[rt] = (lg == 0) ? *(const short8*)(Qsrc + (size_t)r*8) : zfr;
                mreg[rt] = Ml[r];
            }
#pragma unroll
            for (int j = 0; j < 4; ++j) {
                int ut = w + 4*j;
                if (ut < 14) {
#pragma unroll
                    for (int rt = 0; rt < 2; ++rt) {
                        f32x4 e = mfma_bf16(kf[j], qf[rt], zacc);
                        int ubase = ut*16 + lg*4;
                        int r = r0 + rt*16 + l15;
                        float a0 = __builtin_amdgcn_exp2f(e[0]-mreg[rt]);
                        float a1 = __builtin_amdgcn_exp2f(e[1]-mreg[rt]);
                        float a2 = __builtin_amdgcn_exp2f(e[2]-mreg[rt]);
                        float a3 = __builtin_amdgcn_exp2f(e[3]-mreg[rt]);
                        if (HM) {
                            if (ubase+0 == r) a0 = 0.f;
                            if (ubase+1 == r) a1 = 0.f;
                            if (ubase+2 == r) a2 = 0.f;
                            if (ubase+3 == r) a3 = 0.f;
                        }
                        int rl = rt*16 + l15;
                        int s = ((ubase >> 3) + (rl & 7)) % 28;
                        uint2 pk; pk.x = packbf(a0, a1); pk.y = packbf(a2, a3);
                        *(uint2*)((char*)Ah + rl*448 + s*16 + (ubase & 7)*2) = pk;
                    }
                }
            }
        }
        __syncthreads();
        {   // PV phase
#pragma unroll
            for (int rt = 0; rt < 2; ++rt) {
                f32x4 acc = zacc;
                int rl = rt*16 + l15;
#pragma unroll
                for (int ks = 0; ks < 7; ++ks) {
                    int s = (ks*4 + lg + (rl & 7)) % 28;
                    short8 af = *(const short8*)((const char*)Ah + rl*448 + s*16);
                    acc = mfma_bf16(vfr[ks], af, acc);
                }
                int c0 = w*16 + lg*4;
                int r = r0 + rl;
                float gz = g * Zl[r];
#pragma unroll
                for (int reg = 0; reg < 4; ++reg)
                    op[(size_t)(c0+reg)*224 + r] = f2bf(gz*acc[reg]);
            }
        }
        __syncthreads();
    }
}

// ---------------- SE stage 2 ----------------
__global__ __launch_bounds__(256) void k_se2(const float* __restrict__ yMean,
                                             const float* __restrict__ W1,
                                             const float* __restrict__ W2,
                                             float* __restrict__ y2)
{
    int tid = threadIdx.x;
    int b = tid >> 6, c = tid & 63;
    float h[CRv];
#pragma unroll
    for (int j = 0; j < CRv; ++j) {
        float s = 0.f;
#pragma unroll
        for (int cc = 0; cc < CC; ++cc) s += W1[j*CC + cc] * yMean[b*CC + cc];
        h[j] = fmaxf(s * (1.0f/NN), 0.f);
    }
    float s2 = 0.f;
#pragma unroll
    for (int j = 0; j < CRv; ++j) s2 += W2[c*CRv + j] * h[j];
    y2[tid] = 1.f/(1.f + __expf(-s2));
}

// ---------------- final: out = x*(1+y2) + outA^T + outB ----------------
__global__ __launch_bounds__(256) void k_final(const float* __restrict__ x,
                                               const ushort* __restrict__ outA,
                                               const ushort* __restrict__ outB,
                                               const float* __restrict__ y2,
                                               float* __restrict__ out)
{
    __shared__ ushort tile[32][34];
    int bc = blockIdx.z;
    int b = bc >> 6, c = bc & 63;
    int t0 = blockIdx.x*32, r0 = blockIdx.y*32;
    int tx = threadIdx.x & 31, ty = threadIdx.x >> 5;
    float scale = 1.f + y2[bc];
#pragma unroll
    for (int j = 0; j < 4; ++j) {
        int tl = ty + 8*j;
        tile[tl][tx] = outA[((size_t)(b*224 + t0 + tl)*64 + c)*224 + r0 + tx];
    }
    __syncthreads();
#pragma unroll
    for (int j = 0; j < 4; ++j) {
        int rl = ty + 8*j;
        size_t idx = ((size_t)bc*224 + (r0 + rl))*224 + t0 + tx;
        float a = bf2f(tile[tx][rl]);
        float wv = bf2f(outB[((size_t)(b*224 + r0 + rl)*64 + c)*224 + t0 + tx]);
        out[idx] = x[idx]*scale + a + wv;
    }
}

// ---------------- launcher ----------------
extern "C" void kernel_launch(void* const* d_in, const int* in_sizes, int n_in,
                              void* d_out, int out_size, void* d_ws, size_t ws_size,
                              hipStream_t stream)
{
    const float* x  = (const float*)d_in[0];
    const float* Wq = (const float*)d_in[1];
    const float* bq = (const float*)d_in[2];
    const float* Wk = (const float*)d_in[3];
    const float* bk = (const float*)d_in[4];
    const float* Wv = (const float*)d_in[5];
    const float* bv = (const float*)d_in[6];
    const float* gm = (const float*)d_in[7];
    const float* W1 = (const float*)d_in[8];
    const float* W2 = (const float*)d_in[9];
    float* out = (float*)d_out;

    constexpr size_t QSZ = (size_t)BB*NN*CQv;
    constexpr size_t VSZ = (size_t)BB*NN*CC;
    constexpr size_t SSZ = (size_t)BB*NN;

    ushort* qB = (ushort*)d_ws;
    ushort* kB = qB + QSZ;
    ushort* vB = kB + QSZ;
    ushort* qA = vB + VSZ;
    ushort* kA = qA + QSZ;
    ushort* outA = kA + QSZ;
    ushort* outB = outA + VSZ;
    float*  MH = (float*)(outB + VSZ);
    float*  ZH = MH + SSZ;
    float*  MW = ZH + SSZ;
    float*  ZW = MW + SSZ;
    float*  Mf = ZW + SSZ;
    float*  Zi = Mf + SSZ;
    float*  yMean = Zi + SSZ;
    float*  y2    = yMean + 256;
    (void)ws_size; (void)in_sizes; (void)n_in; (void)out_size;

    k_zero<<<1, 256, 0, stream>>>(yMean);
    k_qkv<<<BB*196, 256, 0, stream>>>(x, Wq, bq, Wk, bk, Wv, bv, qB, kB, vB, yMean);
    k_tq<<<dim3(7,7,8), 256, 0, stream>>>((const uint4*)qB, (const uint4*)kB, (uint4*)qA, (uint4*)kA);

    k_scores<<<2*BB*224, 256, 0, stream>>>(qA, kA, qB, kB, MH, ZH, MW, ZW);
    k_combine<<<(BB*NN + 255)/256, 256, 0, stream>>>(MH, ZH, MW, ZW, Mf, Zi);
    k_se2<<<1, 256, 0, stream>>>(yMean, W1, W2, y2);

    k_pv<<<2*BB*224, 256, 0, stream>>>(qA, kA, qB, kB, vB, Mf, Zi, gm, outA, outB);

    k_final<<<dim3(7,7,BB*CC), 256, 0, stream>>>(x, outA, outB, y2, out);
}

// Round 6
// 140.642 us; speedup vs baseline: 6.2425x; 1.1584x over previous
//
#include <hip/hip_runtime.h>
#include <math.h>

#define CC 64
#define CQv 8
#define CRv 4
#define BB 4
#define RR 224
#define TT 224
#define NN (RR*TT)   // 50176
#define LOG2E 1.4426950408889634f

typedef __attribute__((ext_vector_type(8))) short short8;
typedef __attribute__((ext_vector_type(4))) float f32x4;

__device__ __forceinline__ f32x4 mfma_bf16(short8 a, short8 b, f32x4 c){
    return __builtin_amdgcn_mfma_f32_16x16x32_bf16(a, b, c, 0, 0, 0);
}

__device__ __forceinline__ ushort f2bf(float f){
    union { float f; unsigned u; } v; v.f = f;
    unsigned r = v.u + 0x7fffu + ((v.u >> 16) & 1u);
    return (ushort)(r >> 16);
}
__device__ __forceinline__ float bf2f(ushort u){
    return __uint_as_float((unsigned)u << 16);
}
// pack two f32 as truncated bf16 pair: [lo=a, hi=b]
__device__ __forceinline__ unsigned packbf(float a, float b){
    return __builtin_amdgcn_perm(__float_as_uint(b), __float_as_uint(a), 0x07060302u);
}
// balanced XOR swizzle: 512B rows (32 slots of 16B)
__device__ __forceinline__ int vswz(int row, int uslot){
    return (uslot ^ (row & 7) ^ ((row >> 3) & 7)) << 4;
}

// ---------------- K1: q,k,v 1x1 convs via MFMA + per-block mean partials ----------------
// qB[b][pos][8], kB[b][pos][8] (k pre-scaled by log2e), vB[b][pos][64]  (bf16)
__global__ __launch_bounds__(256) void k_qkv(
    const float* __restrict__ x,
    const float* __restrict__ Wq, const float* __restrict__ bq,
    const float* __restrict__ Wk, const float* __restrict__ bk,
    const float* __restrict__ Wv, const float* __restrict__ bv,
    ushort* __restrict__ qB, ushort* __restrict__ kB, ushort* __restrict__ vB,
    float* __restrict__ partial)
{
    const int tid = threadIdx.x;
    const int w = tid >> 6, l = tid & 63, l15 = l & 15, lg = l >> 4;
    const int blk = blockIdx.x;
    const int b = blk / 196, pb = blk - b*196;
    const int n0 = pb*256;
    const float* xb = x + (size_t)b*CC*NN;

    short8 afr[5][2];
#pragma unroll
    for (int ot = 0; ot < 5; ++ot) {
        int oo = ot*16 + l15;
        const float* wr = (oo < 8) ? (Wq + oo*64)
                        : (oo < 16) ? (Wk + (oo-8)*64)
                                    : (Wv + (oo-16)*64);
        float scl = (oo >= 8 && oo < 16) ? LOG2E : 1.0f;
#pragma unroll
        for (int ks = 0; ks < 2; ++ks) {
            const float* p = wr + ks*32 + lg*8;
            float4 w0 = *(const float4*)p, w1 = *(const float4*)(p+4);
            short8 f;
            f[0]=f2bf(w0.x*scl); f[1]=f2bf(w0.y*scl); f[2]=f2bf(w0.z*scl); f[3]=f2bf(w0.w*scl);
            f[4]=f2bf(w1.x*scl); f[5]=f2bf(w1.y*scl); f[6]=f2bf(w1.z*scl); f[7]=f2bf(w1.w*scl);
            afr[ot][ks] = f;
        }
    }
    f32x4 binit[5];
#pragma unroll
    for (int ot = 0; ot < 5; ++ot) {
        const float* bp;
        float scl = 1.0f;
        if (ot == 0) { bp = (lg < 2) ? (bq + lg*4) : (bk + (lg-2)*4); if (lg >= 2) scl = LOG2E; }
        else           bp = bv + (ot-1)*16 + lg*4;
        float4 bb4 = *(const float4*)bp;
        binit[ot] = (f32x4){bb4.x*scl, bb4.y*scl, bb4.z*scl, bb4.w*scl};
    }

    float msum[16];
#pragma unroll
    for (int i = 0; i < 16; ++i) msum[i] = 0.f;

#pragma unroll
    for (int j = 0; j < 4; ++j) {
        int n = n0 + (w*4 + j)*16 + l15;
        short8 bfr[2];
#pragma unroll
        for (int ks = 0; ks < 2; ++ks) {
            const float* xp = xb + (size_t)(ks*32 + lg*8)*NN + n;
            short8 f;
#pragma unroll
            for (int e = 0; e < 8; ++e) {
                float xv = xp[(size_t)e*NN];
                f[e] = f2bf(xv);
                msum[ks*8 + e] += xv;
            }
            bfr[ks] = f;
        }
#pragma unroll
        for (int ot = 0; ot < 5; ++ot) {
            f32x4 acc = binit[ot];
            acc = mfma_bf16(afr[ot][0], bfr[0], acc);
            acc = mfma_bf16(afr[ot][1], bfr[1], acc);
            ushort4 pk;
            pk.x = f2bf(acc[0]); pk.y = f2bf(acc[1]);
            pk.z = f2bf(acc[2]); pk.w = f2bf(acc[3]);
            if (ot == 0) {
                ushort* dst = (lg < 2) ? (qB + ((size_t)b*NN + n)*8 + lg*4)
                                       : (kB + ((size_t)b*NN + n)*8 + (lg-2)*4);
                *(ushort4*)dst = pk;
            } else {
                int oc = (ot-1)*16 + lg*4;
                *(ushort4*)(vB + ((size_t)b*NN + n)*64 + oc) = pk;
            }
        }
    }

#pragma unroll
    for (int i = 0; i < 16; ++i) {
        float s = msum[i];
        s += __shfl_xor(s, 1); s += __shfl_xor(s, 2);
        s += __shfl_xor(s, 4); s += __shfl_xor(s, 8);
        msum[i] = s;
    }
    __shared__ float msums[4][4][16];
    if (l15 == 0) {
#pragma unroll
        for (int i = 0; i < 16; ++i) msums[w][lg][i] = msum[i];
    }
    __syncthreads();
    if (tid < 64) {
        int c = tid;
        int lgi = (c >> 3) & 3, ii = (c >> 5)*8 + (c & 7);
        float t = msums[0][lgi][ii] + msums[1][lgi][ii] + msums[2][lgi][ii] + msums[3][lgi][ii];
        partial[(size_t)blk*64 + c] = t;
    }
}

// ---------------- transpose q/k: [224][224] of 16B units per b (both in one) ----------------
__global__ __launch_bounds__(256) void k_tq(const uint4* __restrict__ qs, const uint4* __restrict__ ks,
                                            uint4* __restrict__ qd, uint4* __restrict__ kd)
{
    __shared__ uint4 tile[32][33];
    int z = blockIdx.z;
    int b = z & 3;
    const uint4* sp = ((z >= 4) ? ks : qs) + (size_t)b*NN;
    uint4*       dp = ((z >= 4) ? kd : qd) + (size_t)b*NN;
    int t0 = blockIdx.x*32, r0 = blockIdx.y*32;
    int tx = threadIdx.x & 31, ty = threadIdx.x >> 5;
#pragma unroll
    for (int j = 0; j < 4; ++j) { int lr = ty + 8*j; tile[lr][tx] = sp[(size_t)(r0+lr)*224 + t0 + tx]; }
    __syncthreads();
#pragma unroll
    for (int j = 0; j < 4; ++j) { int lt = ty + 8*j; dp[(size_t)(t0+lt)*224 + r0 + tx] = tile[tx][lt]; }
}

// ---------------- scores via MFMA: single pass (no max), writes Z only ----------------
__global__ __launch_bounds__(256) void k_scores(const ushort* __restrict__ qA, const ushort* __restrict__ kA,
                                                const ushort* __restrict__ qB, const ushort* __restrict__ kB,
                                                float* __restrict__ ZH, float* __restrict__ ZW)
{
    __shared__ __align__(16) ushort Qh[224*8];
    __shared__ float red[4][224];
    const int tid = threadIdx.x;
    const int bid = blockIdx.x;
    const bool HM = bid < BB*224;
    const int blk = HM ? bid : bid - BB*224;
    const int b = blk / 224, o = blk - b*224;
    const ushort* Qsrc = (HM ? qA : qB) + (size_t)blk*1792;
    const ushort* Ksrc = (HM ? kA : kB) + (size_t)blk*1792;
    if (tid < 224) ((uint4*)Qh)[tid] = ((const uint4*)Qsrc)[tid];
    __syncthreads();
    const int w = tid >> 6, l = tid & 63, l15 = l & 15, lg = l >> 4;
    const short8 zfr = {0,0,0,0,0,0,0,0};
    const f32x4 zacc = {0.f,0.f,0.f,0.f};

    short8 kf[4];
#pragma unroll
    for (int j = 0; j < 4; ++j) {
        int ut = w + 4*j;
        kf[j] = (ut < 14 && lg == 0) ? *(const short8*)(Ksrc + (size_t)(ut*16 + l15)*8) : zfr;
    }
    for (int rt = 0; rt < 14; ++rt) {
        short8 qf = (lg == 0) ? *(const short8*)(Qh + (rt*16 + l15)*8) : zfr;
        float z = 0.f;
#pragma unroll
        for (int j = 0; j < 4; ++j) {
            int ut = w + 4*j;
            if (ut < 14) {
                f32x4 e = mfma_bf16(kf[j], qf, zacc);
#pragma unroll
                for (int g = 0; g < 4; ++g) {
                    bool dg = HM && (ut*16 + lg*4 + g == rt*16 + l15);
                    z += dg ? 0.f : __builtin_amdgcn_exp2f(e[g]);
                }
            }
        }
        z += __shfl_xor(z, 16);
        z += __shfl_xor(z, 32);
        if (lg == 0) red[w][rt*16 + l15] = z;
    }
    __syncthreads();
    if (tid < 224) {
        float z = red[0][tid] + red[1][tid] + red[2][tid] + red[3][tid];
        if (HM) ZH[(size_t)b*NN + (size_t)tid*TT + o] = z;
        else    ZW[(size_t)b*NN + (size_t)o*TT + tid] = z;
    }
}

// ---------------- PV via MFMA: single dispatch, both paths ----------------
__global__ __launch_bounds__(256, 3) void k_pv(const ushort* __restrict__ qA, const ushort* __restrict__ kA,
                                               const ushort* __restrict__ qB, const ushort* __restrict__ kB,
                                               const ushort* __restrict__ vB,
                                               const float* __restrict__ ZH, const float* __restrict__ ZW,
                                               const float* __restrict__ gammap,
                                               ushort* __restrict__ outA, ushort* __restrict__ outB)
{
    __shared__ __align__(16) ushort Vt[64*256];  // bf16 [c][u], XOR-swizzled 512B rows
    __shared__ __align__(16) ushort Ah[32*256];  // bf16 [rl][u], XOR-swizzled
    __shared__ float Zl[224];

    const int tid = threadIdx.x;
    const int bid = blockIdx.x;
    const bool HM = bid < BB*224;
    const int blk = HM ? bid : bid - BB*224;
    const int b = blk / 224, o = blk - b*224;
    const float g = gammap[0];
    const ushort* Qsrc = (HM ? qA : qB) + (size_t)blk*1792;
    const ushort* Ksrc = (HM ? kA : kB) + (size_t)blk*1792;
    ushort* op = (HM ? outA : outB) + (size_t)blk*14336;

    // ---- stage V^T: 4u x 8c register block -> 8x ds_write_b64 (balanced banks)
    {
        const uint4* vbase = (const uint4*)vB;
        for (int gi = tid; gi < 448; gi += 256) {
            int ublk = gi >> 3, sub = gi & 7;
            int u0 = ublk << 2;
            size_t base, stride;
            if (HM) { base = ((size_t)b*NN + (size_t)u0*224 + o)*8 + sub; stride = 1792; }
            else    { base = ((size_t)blk*224 + u0)*8 + sub;              stride = 8;    }
            uint4 r0 = vbase[base], r1 = vbase[base+stride], r2 = vbase[base+2*stride], r3 = vbase[base+3*stride];
            const ushort* p0 = (const ushort*)&r0;
            const ushort* p1 = (const ushort*)&r1;
            const ushort* p2 = (const ushort*)&r2;
            const ushort* p3 = (const ushort*)&r3;
            int half = (ublk & 1) * 8;
#pragma unroll
            for (int j = 0; j < 8; ++j) {
                int c = sub*8 + j;
                ushort4 col; col.x = p0[j]; col.y = p1[j]; col.z = p2[j]; col.w = p3[j];
                *(ushort4*)((char*)Vt + c*512 + vswz(c, ublk >> 1) + half) = col;
            }
        }
    }
    if (tid < 224) {
        size_t sidx = HM ? ((size_t)b*NN + (size_t)tid*TT + o)
                         : ((size_t)b*NN + (size_t)o*TT + tid);
        Zl[tid] = 1.f / (ZH[sidx] + ZW[sidx]);
    }
    __syncthreads();

    const int w = tid >> 6, l = tid & 63;
    const int l15 = l & 15, lg = l >> 4;
    const short8 zfr = {0,0,0,0,0,0,0,0};
    const f32x4 zacc = {0.f,0.f,0.f,0.f};

    // hoisted V^T fragments (A-operand rows = channels)
    short8 vfr[7];
    {
        int c = w*16 + l15;
#pragma unroll
        for (int ks = 0; ks < 7; ++ks)
            vfr[ks] = *(const short8*)((const char*)Vt + c*512 + vswz(c, ks*4 + lg));
    }
    // hoisted K fragments (same tiles for every chunk)
    short8 kf[4];
#pragma unroll
    for (int j = 0; j < 4; ++j) {
        int ut = w + 4*j;
        kf[j] = (ut < 14 && lg == 0) ? *(const short8*)(Ksrc + (size_t)(ut*16 + l15)*8) : zfr;
    }

    for (int ch = 0; ch < 7; ++ch) {
        const int r0 = ch*32;
        {   // score phase: att = exp2(e), truncated bf16, perm-packed
            short8 qf[2];
#pragma unroll
            for (int rt = 0; rt < 2; ++rt) {
                int r = r0 + rt*16 + l15;
                qf[rt] = (lg == 0) ? *(const short8*)(Qsrc + (size_t)r*8) : zfr;
            }
#pragma unroll
            for (int j = 0; j < 4; ++j) {
                int ut = w + 4*j;
                if (ut < 14) {
#pragma unroll
                    for (int rt = 0; rt < 2; ++rt) {
                        f32x4 e = mfma_bf16(kf[j], qf[rt], zacc);
                        int ubase = ut*16 + lg*4;
                        int r = r0 + rt*16 + l15;
                        float a0 = __builtin_amdgcn_exp2f(e[0]);
                        float a1 = __builtin_amdgcn_exp2f(e[1]);
                        float a2 = __builtin_amdgcn_exp2f(e[2]);
                        float a3 = __builtin_amdgcn_exp2f(e[3]);
                        if (HM) {
                            if (ubase+0 == r) a0 = 0.f;
                            if (ubase+1 == r) a1 = 0.f;
                            if (ubase+2 == r) a2 = 0.f;
                            if (ubase+3 == r) a3 = 0.f;
                        }
                        int rl = rt*16 + l15;
                        uint2 pk; pk.x = packbf(a0, a1); pk.y = packbf(a2, a3);
                        *(uint2*)((char*)Ah + rl*512 + vswz(rl, ut*2 + (lg >> 1)) + (lg & 1)*8) = pk;
                    }
                }
            }
        }
        __syncthreads();
        {   // PV phase
#pragma unroll
            for (int rt = 0; rt < 2; ++rt) {
                f32x4 acc = zacc;
                int rl = rt*16 + l15;
#pragma unroll
                for (int ks = 0; ks < 7; ++ks) {
                    short8 af = *(const short8*)((const char*)Ah + rl*512 + vswz(rl, ks*4 + lg));
                    acc = mfma_bf16(vfr[ks], af, acc);
                }
                int c0 = w*16 + lg*4;
                int r = r0 + rl;
                float gz = g * Zl[r];
#pragma unroll
                for (int reg = 0; reg < 4; ++reg)
                    op[(size_t)(c0+reg)*224 + r] = f2bf(gz*acc[reg]);
            }
        }
        __syncthreads();
    }
}

// ---------------- SE stage 2 (reduces mean partials itself) ----------------
__global__ __launch_bounds__(256) void k_se2(const float* __restrict__ partial,
                                             const float* __restrict__ W1,
                                             const float* __restrict__ W2,
                                             float* __restrict__ y2)
{
    __shared__ float mean_s[4][64];
    int tid = threadIdx.x;
    int b = tid >> 6, c = tid & 63;
    float s = 0.f;
    for (int i = 0; i < 196; ++i) s += partial[((size_t)(b*196 + i))*64 + c];
    mean_s[b][c] = s * (1.0f/NN);
    __syncthreads();
    float h[CRv];
#pragma unroll
    for (int j = 0; j < CRv; ++j) {
        float t = 0.f;
#pragma unroll
        for (int cc = 0; cc < CC; ++cc) t += W1[j*CC + cc] * mean_s[b][cc];
        h[j] = fmaxf(t, 0.f);
    }
    float s2 = 0.f;
#pragma unroll
    for (int j = 0; j < CRv; ++j) s2 += W2[c*CRv + j] * h[j];
    y2[tid] = 1.f/(1.f + __expf(-s2));
}

// ---------------- final: out = x*(1+y2) + outA^T + outB ----------------
__global__ __launch_bounds__(256) void k_final(const float* __restrict__ x,
                                               const ushort* __restrict__ outA,
                                               const ushort* __restrict__ outB,
                                               const float* __restrict__ y2,
                                               float* __restrict__ out)
{
    __shared__ ushort tile[32][34];
    int bc = blockIdx.z;
    int b = bc >> 6, c = bc & 63;
    int t0 = blockIdx.x*32, r0 = blockIdx.y*32;
    int tx = threadIdx.x & 31, ty = threadIdx.x >> 5;
    float scale = 1.f + y2[bc];
#pragma unroll
    for (int j = 0; j < 4; ++j) {
        int tl = ty + 8*j;
        tile[tl][tx] = outA[((size_t)(b*224 + t0 + tl)*64 + c)*224 + r0 + tx];
    }
    __syncthreads();
#pragma unroll
    for (int j = 0; j < 4; ++j) {
        int rl = ty + 8*j;
        size_t idx = ((size_t)bc*224 + (r0 + rl))*224 + t0 + tx;
        float a = bf2f(tile[tx][rl]);
        float wv = bf2f(outB[((size_t)(b*224 + r0 + rl)*64 + c)*224 + t0 + tx]);
        out[idx] = x[idx]*scale + a + wv;
    }
}

// ---------------- launcher ----------------
extern "C" void kernel_launch(void* const* d_in, const int* in_sizes, int n_in,
                              void* d_out, int out_size, void* d_ws, size_t ws_size,
                              hipStream_t stream)
{
    const float* x  = (const float*)d_in[0];
    const float* Wq = (const float*)d_in[1];
    const float* bq = (const float*)d_in[2];
    const float* Wk = (const float*)d_in[3];
    const float* bk = (const float*)d_in[4];
    const float* Wv = (const float*)d_in[5];
    const float* bv = (const float*)d_in[6];
    const float* gm = (const float*)d_in[7];
    const float* W1 = (const float*)d_in[8];
    const float* W2 = (const float*)d_in[9];
    float* out = (float*)d_out;

    constexpr size_t QSZ = (size_t)BB*NN*CQv;
    constexpr size_t VSZ = (size_t)BB*NN*CC;
    constexpr size_t SSZ = (size_t)BB*NN;

    ushort* qB = (ushort*)d_ws;
    ushort* kB = qB + QSZ;
    ushort* vB = kB + QSZ;
    ushort* qA = vB + VSZ;
    ushort* kA = qA + QSZ;
    ushort* outA = kA + QSZ;
    ushort* outB = outA + VSZ;
    float*  ZH = (float*)(outB + VSZ);
    float*  ZW = ZH + SSZ;
    float*  partial = ZW + SSZ;        // BB*196*64 = 50176 floats
    float*  y2 = partial + (size_t)BB*196*64;
    (void)ws_size; (void)in_sizes; (void)n_in; (void)out_size;

    k_qkv<<<BB*196, 256, 0, stream>>>(x, Wq, bq, Wk, bk, Wv, bv, qB, kB, vB, partial);
    k_tq<<<dim3(7,7,8), 256, 0, stream>>>((const uint4*)qB, (const uint4*)kB, (uint4*)qA, (uint4*)kA);

    k_scores<<<2*BB*224, 256, 0, stream>>>(qA, kA, qB, kB, ZH, ZW);
    k_se2<<<1, 256, 0, stream>>>(partial, W1, W2, y2);

    k_pv<<<2*BB*224, 256, 0, stream>>>(qA, kA, qB, kB, vB, ZH, ZW, gm, outA, outB);

    k_final<<<dim3(7,7,BB*CC), 256, 0, stream>>>(x, outA, outB, y2, out);
}

// Round 7
// 119.982 us; speedup vs baseline: 7.3174x; 1.1722x over previous
//
#include <hip/hip_runtime.h>
#include <math.h>

#define CC 64
#define CQv 8
#define CRv 4
#define BB 4
#define RR 224
#define TT 224
#define NN (RR*TT)   // 50176
#define LOG2E 1.4426950408889634f

typedef __attribute__((ext_vector_type(8))) short short8;
typedef __attribute__((ext_vector_type(4))) float f32x4;

__device__ __forceinline__ f32x4 mfma_bf16(short8 a, short8 b, f32x4 c){
    return __builtin_amdgcn_mfma_f32_16x16x32_bf16(a, b, c, 0, 0, 0);
}

__device__ __forceinline__ ushort f2bf(float f){
    union { float f; unsigned u; } v; v.f = f;
    unsigned r = v.u + 0x7fffu + ((v.u >> 16) & 1u);
    return (ushort)(r >> 16);
}
__device__ __forceinline__ float bf2f(ushort u){
    return __uint_as_float((unsigned)u << 16);
}
// pack two f32 as truncated bf16 pair: [lo=a, hi=b]
__device__ __forceinline__ unsigned packbf(float a, float b){
    return __builtin_amdgcn_perm(__float_as_uint(b), __float_as_uint(a), 0x07060302u);
}
// balanced XOR swizzle: 512B rows (32 slots of 16B)
__device__ __forceinline__ int vswz(int row, int uslot){
    return (uslot ^ (row & 7) ^ ((row >> 3) & 7)) << 4;
}

// ---------------- K1: q,k,v 1x1 convs via MFMA + per-block mean partials ----------------
// qB[b][pos][8], kB[b][pos][8] (k pre-scaled by log2e), vB[b][pos][64]  (bf16)
__global__ __launch_bounds__(256) void k_qkv(
    const float* __restrict__ x,
    const float* __restrict__ Wq, const float* __restrict__ bq,
    const float* __restrict__ Wk, const float* __restrict__ bk,
    const float* __restrict__ Wv, const float* __restrict__ bv,
    ushort* __restrict__ qB, ushort* __restrict__ kB, ushort* __restrict__ vB,
    float* __restrict__ partial)
{
    const int tid = threadIdx.x;
    const int w = tid >> 6, l = tid & 63, l15 = l & 15, lg = l >> 4;
    const int blk = blockIdx.x;
    const int b = blk / 196, pb = blk - b*196;
    const int n0 = pb*256;
    const float* xb = x + (size_t)b*CC*NN;

    short8 afr[5][2];
#pragma unroll
    for (int ot = 0; ot < 5; ++ot) {
        int oo = ot*16 + l15;
        const float* wr = (oo < 8) ? (Wq + oo*64)
                        : (oo < 16) ? (Wk + (oo-8)*64)
                                    : (Wv + (oo-16)*64);
        float scl = (oo >= 8 && oo < 16) ? LOG2E : 1.0f;
#pragma unroll
        for (int ks = 0; ks < 2; ++ks) {
            const float* p = wr + ks*32 + lg*8;
            float4 w0 = *(const float4*)p, w1 = *(const float4*)(p+4);
            short8 f;
            f[0]=f2bf(w0.x*scl); f[1]=f2bf(w0.y*scl); f[2]=f2bf(w0.z*scl); f[3]=f2bf(w0.w*scl);
            f[4]=f2bf(w1.x*scl); f[5]=f2bf(w1.y*scl); f[6]=f2bf(w1.z*scl); f[7]=f2bf(w1.w*scl);
            afr[ot][ks] = f;
        }
    }
    f32x4 binit[5];
#pragma unroll
    for (int ot = 0; ot < 5; ++ot) {
        const float* bp;
        float scl = 1.0f;
        if (ot == 0) { bp = (lg < 2) ? (bq + lg*4) : (bk + (lg-2)*4); if (lg >= 2) scl = LOG2E; }
        else           bp = bv + (ot-1)*16 + lg*4;
        float4 bb4 = *(const float4*)bp;
        binit[ot] = (f32x4){bb4.x*scl, bb4.y*scl, bb4.z*scl, bb4.w*scl};
    }

    float msum[16];
#pragma unroll
    for (int i = 0; i < 16; ++i) msum[i] = 0.f;

#pragma unroll
    for (int j = 0; j < 4; ++j) {
        int n = n0 + (w*4 + j)*16 + l15;
        short8 bfr[2];
#pragma unroll
        for (int ks = 0; ks < 2; ++ks) {
            const float* xp = xb + (size_t)(ks*32 + lg*8)*NN + n;
            short8 f;
#pragma unroll
            for (int e = 0; e < 8; ++e) {
                float xv = xp[(size_t)e*NN];
                f[e] = f2bf(xv);
                msum[ks*8 + e] += xv;
            }
            bfr[ks] = f;
        }
#pragma unroll
        for (int ot = 0; ot < 5; ++ot) {
            f32x4 acc = binit[ot];
            acc = mfma_bf16(afr[ot][0], bfr[0], acc);
            acc = mfma_bf16(afr[ot][1], bfr[1], acc);
            ushort4 pk;
            pk.x = f2bf(acc[0]); pk.y = f2bf(acc[1]);
            pk.z = f2bf(acc[2]); pk.w = f2bf(acc[3]);
            if (ot == 0) {
                ushort* dst = (lg < 2) ? (qB + ((size_t)b*NN + n)*8 + lg*4)
                                       : (kB + ((size_t)b*NN + n)*8 + (lg-2)*4);
                *(ushort4*)dst = pk;
            } else {
                int oc = (ot-1)*16 + lg*4;
                *(ushort4*)(vB + ((size_t)b*NN + n)*64 + oc) = pk;
            }
        }
    }

#pragma unroll
    for (int i = 0; i < 16; ++i) {
        float s = msum[i];
        s += __shfl_xor(s, 1); s += __shfl_xor(s, 2);
        s += __shfl_xor(s, 4); s += __shfl_xor(s, 8);
        msum[i] = s;
    }
    __shared__ float msums[4][4][16];
    if (l15 == 0) {
#pragma unroll
        for (int i = 0; i < 16; ++i) msums[w][lg][i] = msum[i];
    }
    __syncthreads();
    if (tid < 64) {
        int c = tid;
        int lgi = (c >> 3) & 3, ii = (c >> 5)*8 + (c & 7);
        float t = msums[0][lgi][ii] + msums[1][lgi][ii] + msums[2][lgi][ii] + msums[3][lgi][ii];
        partial[(size_t)blk*64 + c] = t;
    }
}

// ---------------- transpose q/k: [224][224] of 16B units per b (both in one) ----------------
__global__ __launch_bounds__(256) void k_tq(const uint4* __restrict__ qs, const uint4* __restrict__ ks,
                                            uint4* __restrict__ qd, uint4* __restrict__ kd)
{
    __shared__ uint4 tile[32][33];
    int z = blockIdx.z;
    int b = z & 3;
    const uint4* sp = ((z >= 4) ? ks : qs) + (size_t)b*NN;
    uint4*       dp = ((z >= 4) ? kd : qd) + (size_t)b*NN;
    int t0 = blockIdx.x*32, r0 = blockIdx.y*32;
    int tx = threadIdx.x & 31, ty = threadIdx.x >> 5;
#pragma unroll
    for (int j = 0; j < 4; ++j) { int lr = ty + 8*j; tile[lr][tx] = sp[(size_t)(r0+lr)*224 + t0 + tx]; }
    __syncthreads();
#pragma unroll
    for (int j = 0; j < 4; ++j) { int lt = ty + 8*j; dp[(size_t)(t0+lt)*224 + r0 + tx] = tile[tx][lt]; }
}

// ---------------- PV via MFMA: unnormalized out + row-sum Z (scores fused) ----------------
__global__ __launch_bounds__(256, 3) void k_pv(const ushort* __restrict__ qA, const ushort* __restrict__ kA,
                                               const ushort* __restrict__ qB, const ushort* __restrict__ kB,
                                               const ushort* __restrict__ vB,
                                               ushort* __restrict__ outA, ushort* __restrict__ outB,
                                               float* __restrict__ ZHt, float* __restrict__ ZWt)
{
    __shared__ __align__(16) ushort Vt[64*256];  // bf16 [c][u], XOR-swizzled 512B rows
    __shared__ __align__(16) ushort Ah[32*256];  // bf16 [rl][u], XOR-swizzled
    __shared__ float zred[4][32];

    const int tid = threadIdx.x;
    const int bid = blockIdx.x;
    const bool HM = bid < BB*224;
    const int blk = HM ? bid : bid - BB*224;
    const int b = blk / 224, o = blk - b*224;
    const ushort* Qsrc = (HM ? qA : qB) + (size_t)blk*1792;
    const ushort* Ksrc = (HM ? kA : kB) + (size_t)blk*1792;
    ushort* op = (HM ? outA : outB) + (size_t)blk*14336;
    float*  Zt = (HM ? ZHt : ZWt) + (size_t)blk*224;

    // ---- stage V^T: 4u x 8c register block -> 8x ds_write_b64 (balanced banks)
    {
        const uint4* vbase = (const uint4*)vB;
        for (int gi = tid; gi < 448; gi += 256) {
            int ublk = gi >> 3, sub = gi & 7;
            int u0 = ublk << 2;
            size_t base, stride;
            if (HM) { base = ((size_t)b*NN + (size_t)u0*224 + o)*8 + sub; stride = 1792; }
            else    { base = ((size_t)blk*224 + u0)*8 + sub;              stride = 8;    }
            uint4 r0 = vbase[base], r1 = vbase[base+stride], r2 = vbase[base+2*stride], r3 = vbase[base+3*stride];
            const ushort* p0 = (const ushort*)&r0;
            const ushort* p1 = (const ushort*)&r1;
            const ushort* p2 = (const ushort*)&r2;
            const ushort* p3 = (const ushort*)&r3;
            int half = (ublk & 1) * 8;
#pragma unroll
            for (int j = 0; j < 8; ++j) {
                int c = sub*8 + j;
                ushort4 col; col.x = p0[j]; col.y = p1[j]; col.z = p2[j]; col.w = p3[j];
                *(ushort4*)((char*)Vt + c*512 + vswz(c, ublk >> 1) + half) = col;
            }
        }
    }
    __syncthreads();

    const int w = tid >> 6, l = tid & 63;
    const int l15 = l & 15, lg = l >> 4;
    const short8 zfr = {0,0,0,0,0,0,0,0};
    const f32x4 zacc = {0.f,0.f,0.f,0.f};

    // hoisted V^T fragments (A-operand rows = channels)
    short8 vfr[7];
    {
        int c = w*16 + l15;
#pragma unroll
        for (int ks = 0; ks < 7; ++ks)
            vfr[ks] = *(const short8*)((const char*)Vt + c*512 + vswz(c, ks*4 + lg));
    }
    // hoisted K fragments (same tiles for every chunk)
    short8 kf[4];
#pragma unroll
    for (int j = 0; j < 4; ++j) {
        int ut = w + 4*j;
        kf[j] = (ut < 14 && lg == 0) ? *(const short8*)(Ksrc + (size_t)(ut*16 + l15)*8) : zfr;
    }

    for (int ch = 0; ch < 7; ++ch) {
        const int r0 = ch*32;
        {   // score phase: att = exp2(e), truncated bf16, perm-packed; z accumulated
            short8 qf[2];
            float zp[2] = {0.f, 0.f};
#pragma unroll
            for (int rt = 0; rt < 2; ++rt) {
                int r = r0 + rt*16 + l15;
                qf[rt] = (lg == 0) ? *(const short8*)(Qsrc + (size_t)r*8) : zfr;
            }
#pragma unroll
            for (int j = 0; j < 4; ++j) {
                int ut = w + 4*j;
                if (ut < 14) {
#pragma unroll
                    for (int rt = 0; rt < 2; ++rt) {
                        f32x4 e = mfma_bf16(kf[j], qf[rt], zacc);
                        int ubase = ut*16 + lg*4;
                        int r = r0 + rt*16 + l15;
                        float a0 = __builtin_amdgcn_exp2f(e[0]);
                        float a1 = __builtin_amdgcn_exp2f(e[1]);
                        float a2 = __builtin_amdgcn_exp2f(e[2]);
                        float a3 = __builtin_amdgcn_exp2f(e[3]);
                        if (HM) {
                            if (ubase+0 == r) a0 = 0.f;
                            if (ubase+1 == r) a1 = 0.f;
                            if (ubase+2 == r) a2 = 0.f;
                            if (ubase+3 == r) a3 = 0.f;
                        }
                        zp[rt] += (a0 + a1) + (a2 + a3);
                        int rl = rt*16 + l15;
                        uint2 pk; pk.x = packbf(a0, a1); pk.y = packbf(a2, a3);
                        *(uint2*)((char*)Ah + rl*512 + vswz(rl, ut*2 + (lg >> 1)) + (lg & 1)*8) = pk;
                    }
                }
            }
            // cross-lg reduce of z partials (lanes with same l15 share a row)
#pragma unroll
            for (int rt = 0; rt < 2; ++rt) {
                float z = zp[rt];
                z += __shfl_xor(z, 16);
                z += __shfl_xor(z, 32);
                if (lg == 0) zred[w][rt*16 + l15] = z;
            }
        }
        __syncthreads();
        if (tid < 32)
            Zt[r0 + tid] = (zred[0][tid] + zred[1][tid]) + (zred[2][tid] + zred[3][tid]);
        {   // PV phase (unnormalized)
#pragma unroll
            for (int rt = 0; rt < 2; ++rt) {
                f32x4 acc = zacc;
                int rl = rt*16 + l15;
#pragma unroll
                for (int ks = 0; ks < 7; ++ks) {
                    short8 af = *(const short8*)((const char*)Ah + rl*512 + vswz(rl, ks*4 + lg));
                    acc = mfma_bf16(vfr[ks], af, acc);
                }
                int c0 = w*16 + lg*4;
                int r = r0 + rl;
#pragma unroll
                for (int reg = 0; reg < 4; ++reg)
                    op[(size_t)(c0+reg)*224 + r] = f2bf(acc[reg]);
            }
        }
        __syncthreads();
    }
}

// ---------------- aux: Zi = g*rcp(ZH^T + ZW) tiles (blocks 0..195) + SE (block 196) ----------------
__global__ __launch_bounds__(256) void k_aux(const float* __restrict__ ZHt, const float* __restrict__ ZWt,
                                             const float* __restrict__ gammap,
                                             const float* __restrict__ partial,
                                             const float* __restrict__ W1, const float* __restrict__ W2,
                                             float* __restrict__ Zi, float* __restrict__ y2)
{
    const int blk = blockIdx.x;
    if (blk < 196) {
        __shared__ float tile[32][33];
        int b = blk / 49, rem = blk - b*49;
        int t0 = (rem % 7)*32, v0 = (rem / 7)*32;
        int tx = threadIdx.x & 31, ty = threadIdx.x >> 5;
        float g = gammap[0];
#pragma unroll
        for (int j = 0; j < 4; ++j) {
            int tl = ty + 8*j;
            tile[tl][tx] = ZHt[((size_t)(b*224 + t0 + tl))*224 + v0 + tx];
        }
        __syncthreads();
#pragma unroll
        for (int j = 0; j < 4; ++j) {
            int vl = ty + 8*j;
            size_t i = ((size_t)(b*224 + v0 + vl))*224 + t0 + tx;
            float zs = tile[tx][vl] + ZWt[i];
            Zi[i] = g * __builtin_amdgcn_rcpf(zs);
        }
    } else {
        __shared__ float mean_s[4][64];
        int tid = threadIdx.x;
        int b = tid >> 6, c = tid & 63;
        float s = 0.f;
        for (int i = 0; i < 196; ++i) s += partial[((size_t)(b*196 + i))*64 + c];
        mean_s[b][c] = s * (1.0f/NN);
        __syncthreads();
        float h[CRv];
#pragma unroll
        for (int j = 0; j < CRv; ++j) {
            float t = 0.f;
#pragma unroll
            for (int cc = 0; cc < CC; ++cc) t += W1[j*CC + cc] * mean_s[b][cc];
            h[j] = fmaxf(t, 0.f);
        }
        float s2 = 0.f;
#pragma unroll
        for (int j = 0; j < CRv; ++j) s2 += W2[c*CRv + j] * h[j];
        y2[tid] = 1.f/(1.f + __expf(-s2));
    }
}

// ---------------- final: out = x*(1+y2) + (outA^T + outB)*Zi ----------------
__global__ __launch_bounds__(256) void k_final(const float* __restrict__ x,
                                               const ushort* __restrict__ outA,
                                               const ushort* __restrict__ outB,
                                               const float* __restrict__ Zi,
                                               const float* __restrict__ y2,
                                               float* __restrict__ out)
{
    __shared__ ushort tile[32][34];
    int bc = blockIdx.z;
    int b = bc >> 6, c = bc & 63;
    int t0 = blockIdx.x*32, r0 = blockIdx.y*32;
    int tx = threadIdx.x & 31, ty = threadIdx.x >> 5;
    float scale = 1.f + y2[bc];
#pragma unroll
    for (int j = 0; j < 4; ++j) {
        int tl = ty + 8*j;
        tile[tl][tx] = outA[((size_t)(b*224 + t0 + tl)*64 + c)*224 + r0 + tx];
    }
    __syncthreads();
#pragma unroll
    for (int j = 0; j < 4; ++j) {
        int rl = ty + 8*j;
        size_t pidx = (size_t)(r0 + rl)*224 + t0 + tx;
        size_t idx = (size_t)bc*NN + pidx;
        float a = bf2f(tile[tx][rl]);
        float wv = bf2f(outB[((size_t)(b*224 + r0 + rl)*64 + c)*224 + t0 + tx]);
        float zi = Zi[(size_t)b*NN + pidx];
        out[idx] = x[idx]*scale + (a + wv)*zi;
    }
}

// ---------------- launcher ----------------
extern "C" void kernel_launch(void* const* d_in, const int* in_sizes, int n_in,
                              void* d_out, int out_size, void* d_ws, size_t ws_size,
                              hipStream_t stream)
{
    const float* x  = (const float*)d_in[0];
    const float* Wq = (const float*)d_in[1];
    const float* bq = (const float*)d_in[2];
    const float* Wk = (const float*)d_in[3];
    const float* bk = (const float*)d_in[4];
    const float* Wv = (const float*)d_in[5];
    const float* bv = (const float*)d_in[6];
    const float* gm = (const float*)d_in[7];
    const float* W1 = (const float*)d_in[8];
    const float* W2 = (const float*)d_in[9];
    float* out = (float*)d_out;

    constexpr size_t QSZ = (size_t)BB*NN*CQv;
    constexpr size_t VSZ = (size_t)BB*NN*CC;
    constexpr size_t SSZ = (size_t)BB*NN;

    ushort* qB = (ushort*)d_ws;
    ushort* kB = qB + QSZ;
    ushort* vB = kB + QSZ;
    ushort* qA = vB + VSZ;
    ushort* kA = qA + QSZ;
    ushort* outA = kA + QSZ;
    ushort* outB = outA + VSZ;
    float*  ZHt = (float*)(outB + VSZ);
    float*  ZWt = ZHt + SSZ;
    float*  Zi  = ZWt + SSZ;
    float*  partial = Zi + SSZ;        // BB*196*64 = 50176 floats
    float*  y2 = partial + (size_t)BB*196*64;
    (void)ws_size; (void)in_sizes; (void)n_in; (void)out_size;

    k_qkv<<<BB*196, 256, 0, stream>>>(x, Wq, bq, Wk, bk, Wv, bv, qB, kB, vB, partial);
    k_tq<<<dim3(7,7,8), 256, 0, stream>>>((const uint4*)qB, (const uint4*)kB, (uint4*)qA, (uint4*)kA);

    k_pv<<<2*BB*224, 256, 0, stream>>>(qA, kA, qB, kB, vB, outA, outB, ZHt, ZWt);
    k_aux<<<197, 256, 0, stream>>>(ZHt, ZWt, gm, partial, W1, W2, Zi, y2);

    k_final<<<dim3(7,7,BB*CC), 256, 0, stream>>>(x, outA, outB, Zi, y2, out);
}